// Round 11
// baseline (851.930 us; speedup 1.0000x reference)
//
#include <hip/hip_runtime.h>
#include <hip/hip_bf16.h>

// GCN layer: h = BN(ReLU(segment_sum(norm * (nf@W))[col] + b))
// R1: CSR gather.  R2: bf16 table.  R4: block-reservation radix partition.
// R5: fold dinv into tab.  R6: MFMA bf16 GEMM, bf16 h.
// R8: zero-waste wave-per-node gather (proven 107us; R7/R9 restructures both
//     regressed -> gather is at the ~3.5TB/s random-256B fabric ceiling).
// R10: revert gather to R8 structure (w/ bf16-bits weight decode);
//      gemm: drop W LDS stage (32KB wtb is L1/L2-resident) -> 4 blocks/CU;
//      merge the two scan kernels.

#define BKT_BITS 7
#define BKT_SZ 128
#define MAX_BKT 1024        // N <= 131072 (row fits 17 bits)
#define CHUNK 8192

typedef __attribute__((ext_vector_type(8))) short bf16x8;
typedef __attribute__((ext_vector_type(4))) float f32x4;

__device__ __forceinline__ unsigned bf16rn(float f) {
    unsigned x = __float_as_uint(f);
    return (x + 0x7fffu + ((x >> 16) & 1u)) >> 16;
}
__device__ __forceinline__ float bflo(unsigned u) { return __uint_as_float(u << 16); }
__device__ __forceinline__ float bfhi(unsigned u) { return __uint_as_float(u & 0xffff0000u); }

// ---------------- path 1: single-histogram radix partition ----------------
// + convW folded into block 0
__global__ __launch_bounds__(256) void k_bhist2(const int* __restrict__ col,
        int* __restrict__ blkoff, const float* __restrict__ Wm,
        unsigned* __restrict__ WT, int E, int nb, int nbc) {
    __shared__ int h[MAX_BKT];
    for (int i = threadIdx.x; i < nb; i += 256) h[i] = 0;
    __syncthreads();
    int base = blockIdx.x * CHUNK, lim = min(base + CHUNK, E);
    for (int e = base + threadIdx.x; e < lim; e += 256)
        atomicAdd(&h[col[e] >> BKT_BITS], 1);
    __syncthreads();
    for (int i = threadIdx.x; i < nb; i += 256)
        blkoff[(size_t)i * nbc + blockIdx.x] = h[i];
    if (blockIdx.x == 0) {
        // WT[j][k2] = bf16(W[2k2][j]) | bf16(W[2k2+1][j])<<16
        for (int i = threadIdx.x; i < 128 * 64; i += 256) {
            int j = i >> 6, w = i & 63;
            float a = Wm[(size_t)(2 * w) * 128 + j];
            float b = Wm[(size_t)(2 * w + 1) * 128 + j];
            WT[i] = bf16rn(a) | (bf16rn(b) << 16);
        }
    }
}

// merged scan: per-bucket scan over blocks + block-wide scan of totals
__global__ __launch_bounds__(1024) void k_bscanM(int* __restrict__ blkoff,
        int* __restrict__ bbase, int* __restrict__ ptr, float* __restrict__ sums,
        int nb, int nbc, int N, int E) {
    __shared__ int ls[1024];
    int t = threadIdx.x;
    int run = 0;
    if (t < nb) {
        int* p = blkoff + (size_t)t * nbc;
        for (int i = 0; i < nbc; ++i) { int c = p[i]; p[i] = run; run += c; }
    }
    ls[t] = run;
    __syncthreads();
    for (int off = 1; off < 1024; off <<= 1) {
        int u = (t >= off) ? ls[t - off] : 0;
        __syncthreads();
        ls[t] += u;
        __syncthreads();
    }
    if (t < nb) bbase[t] = ls[t] - run;
    if (t == nb - 1) bbase[nb] = ls[t];
    if (t == 0) ptr[N] = E;
    if (t < 512) sums[t] = 0.0f;
}

// scatter into bucket-grouped tmp: rec = row17<<15 | col7<<8 | w8
__global__ __launch_bounds__(256) void k_passA3(
        const int* __restrict__ row, const int* __restrict__ col,
        const float* __restrict__ w, const int* __restrict__ blkoff,
        const int* __restrict__ bbase, unsigned* __restrict__ tmp,
        int E, int nb, int nbc) {
    __shared__ int cur[MAX_BKT];
    for (int i = threadIdx.x; i < nb; i += 256)
        cur[i] = bbase[i] + blkoff[(size_t)i * nbc + blockIdx.x];
    __syncthreads();
    int base = blockIdx.x * CHUNK, lim = min(base + CHUNK, E);
    for (int e = base + threadIdx.x; e < lim; e += 256) {
        int c = col[e];
        int q8 = (int)(w[e] * 256.0f + 0.5f);
        if (q8 > 255) q8 = 255;
        unsigned rec = ((unsigned)row[e] << 15) | ((unsigned)(c & 127) << 8) | (unsigned)q8;
        int pos = atomicAdd(&cur[c >> BKT_BITS], 1);
        tmp[pos] = rec;
    }
}

// pass B: per-node offsets in LDS, place edges as row17|wbf15
// (wbf15 = bf16 bits of w*dinv[col], <0x8000), fused degree -> dinv.
__global__ __launch_bounds__(256) void k_passB2(
        const unsigned* __restrict__ tmp, const int* __restrict__ bbase,
        unsigned* __restrict__ packed, int* __restrict__ ptr,
        float* __restrict__ dinv, int N) {
    __shared__ int hcnt[BKT_SZ];
    __shared__ int wsumi[BKT_SZ];
    __shared__ int cur[BKT_SZ];
    __shared__ float dcl[BKT_SZ];
    int b = blockIdx.x;
    int t = threadIdx.x;
    if (t < BKT_SZ) { hcnt[t] = 0; wsumi[t] = 0; }
    __syncthreads();
    int beg = bbase[b], end = bbase[b + 1];
    for (int k = beg + t; k < end; k += 256) {
        unsigned p = tmp[k];
        int li = (p >> 8) & 127;
        atomicAdd(&hcnt[li], 1);
        atomicAdd(&wsumi[li], (int)(p & 255u));
    }
    __syncthreads();
    if (t < BKT_SZ) cur[t] = hcnt[t];
    __syncthreads();
    for (int off = 1; off < BKT_SZ; off <<= 1) {
        int v = (t < BKT_SZ && t >= off) ? cur[t - off] : 0;
        __syncthreads();
        if (t < BKT_SZ) cur[t] += v;
        __syncthreads();
    }
    if (t < BKT_SZ) {
        int p = beg + cur[t] - hcnt[t];
        cur[t] = p;
        float d = 1.0f + (float)wsumi[t] * (1.0f / 256.0f);
        float dc = rsqrtf(d);
        dcl[t] = dc;
        int n = (b << BKT_BITS) + t;
        if (n < N) { ptr[n] = p; dinv[n] = dc; }
    }
    __syncthreads();
    for (int k = beg + t; k < end; k += 256) {
        unsigned p = tmp[k];
        int li = (p >> 8) & 127;
        int pos = atomicAdd(&cur[li], 1);
        float fw = (float)(p & 255u) * (1.0f / 256.0f) * dcl[li];
        unsigned wb = bf16rn(fw) & 0x7FFFu;
        packed[pos] = ((p >> 15) << 15) | wb;
    }
}

// tab[r] = bf16(nf[r] * dinv[r])
__global__ void k_conv2(const float* __restrict__ nf, const float* __restrict__ dinv,
                        uint4* __restrict__ tab, int N) {
    size_t i = (size_t)blockIdx.x * 256 + threadIdx.x;
    if (i >= (size_t)N * 16) return;
    int n = (int)(i >> 4);
    float dv = dinv[n];
    const float4* src = (const float4*)nf + 2 * i;
    float4 a = src[0], b = src[1];
    uint4 r;
    r.x = bf16rn(a.x * dv) | (bf16rn(a.y * dv) << 16);
    r.y = bf16rn(a.z * dv) | (bf16rn(a.w * dv) << 16);
    r.z = bf16rn(b.x * dv) | (bf16rn(b.y * dv) << 16);
    r.w = bf16rn(b.z * dv) | (bf16rn(b.w * dv) << 16);
    tab[i] = r;
}

#define EDGE_FMA(aX, nX, tX)                                     \
    aX[0] += nX * bflo(tX.x); aX[1] += nX * bfhi(tX.x);          \
    aX[2] += nX * bflo(tX.y); aX[3] += nX * bfhi(tX.y);          \
    aX[4] += nX * bflo(tX.z); aX[5] += nX * bfhi(tX.z);          \
    aX[6] += nX * bflo(tX.w); aX[7] += nX * bfhi(tX.w);

// gather (R8 structure): wave per node; uncond 4-deep main, 2-deep mid,
// exec-masked tail. rec = row17|wbf15; dinv[row] folded in tab.
__global__ __launch_bounds__(256) void k_gatherw5(
        const unsigned* __restrict__ packed, const int* __restrict__ ptr,
        const float* __restrict__ dinv, const unsigned* __restrict__ tab,
        unsigned* __restrict__ aggb, int N) {
    int wid = (int)(((size_t)blockIdx.x * 256 + threadIdx.x) >> 6);
    int lane = threadIdx.x & 63;
    if (wid >= N) return;
    int beg = ptr[wid], end = ptr[wid + 1];
    float dc = dinv[wid];
    int q = lane >> 4;       // edge slot
    int fl = lane & 15;      // features [8*fl, 8*fl+8)
    float a0[8] = {}, a1[8] = {}, a2[8] = {}, a3[8] = {};
    int k = beg;
    for (; k + 16 <= end; k += 16) {
        unsigned p0 = packed[k + q];
        unsigned p1 = packed[k + 4 + q];
        unsigned p2 = packed[k + 8 + q];
        unsigned p3 = packed[k + 12 + q];
        uint4 t0 = *(const uint4*)(tab + (size_t)(p0 >> 15) * 64 + fl * 4);
        uint4 t1 = *(const uint4*)(tab + (size_t)(p1 >> 15) * 64 + fl * 4);
        uint4 t2 = *(const uint4*)(tab + (size_t)(p2 >> 15) * 64 + fl * 4);
        uint4 t3 = *(const uint4*)(tab + (size_t)(p3 >> 15) * 64 + fl * 4);
        float n0 = bflo(p0 & 0x7FFFu);
        float n1 = bflo(p1 & 0x7FFFu);
        float n2 = bflo(p2 & 0x7FFFu);
        float n3 = bflo(p3 & 0x7FFFu);
        EDGE_FMA(a0, n0, t0)
        EDGE_FMA(a1, n1, t1)
        EDGE_FMA(a2, n2, t2)
        EDGE_FMA(a3, n3, t3)
    }
    if (k + 8 <= end) {
        unsigned p0 = packed[k + q];
        unsigned p1 = packed[k + 4 + q];
        uint4 t0 = *(const uint4*)(tab + (size_t)(p0 >> 15) * 64 + fl * 4);
        uint4 t1 = *(const uint4*)(tab + (size_t)(p1 >> 15) * 64 + fl * 4);
        float n0 = bflo(p0 & 0x7FFFu);
        float n1 = bflo(p1 & 0x7FFFu);
        EDGE_FMA(a0, n0, t0)
        EDGE_FMA(a1, n1, t1)
        k += 8;
    }
    for (; k < end; k += 4) {
        int i0 = k + q;
        if (i0 < end) {      // exec-masked: no loads from invalid lanes
            unsigned p0 = packed[i0];
            uint4 t0 = *(const uint4*)(tab + (size_t)(p0 >> 15) * 64 + fl * 4);
            float n0 = bflo(p0 & 0x7FFFu);
            EDGE_FMA(a0, n0, t0)
        }
    }
#pragma unroll
    for (int j = 0; j < 8; ++j) {
        float s = (a0[j] + a1[j]) + (a2[j] + a3[j]);
        s += __shfl_xor(s, 16);
        s += __shfl_xor(s, 32);
        a0[j] = s;
    }
    if (q == 0) {
        uint4 t = *(const uint4*)(tab + (size_t)wid * 64 + fl * 4);
        EDGE_FMA(a0, dc, t)   // self: dc*tab[c]
        uint4 r;
        r.x = bf16rn(a0[0]) | (bf16rn(a0[1]) << 16);
        r.y = bf16rn(a0[2]) | (bf16rn(a0[3]) << 16);
        r.z = bf16rn(a0[4]) | (bf16rn(a0[5]) << 16);
        r.w = bf16rn(a0[6]) | (bf16rn(a0[7]) << 16);
        *(uint4*)(aggb + (size_t)wid * 64 + fl * 4) = r;
    }
}

// gather -> f32 rows into out (path-2 fallback; same packed format)
__global__ __launch_bounds__(256) void k_gatherwF(
        const unsigned* __restrict__ packed, const int* __restrict__ ptr,
        const float* __restrict__ dinv, const unsigned* __restrict__ tab,
        float* __restrict__ out, int N) {
    int wid = (int)(((size_t)blockIdx.x * 256 + threadIdx.x) >> 6);
    int lane = threadIdx.x & 63;
    if (wid >= N) return;
    int beg = ptr[wid], end = ptr[wid + 1];
    float dc = dinv[wid];
    int q = lane >> 4;
    int fl = lane & 15;
    float a0[8] = {}, a1[8] = {};
    int k = beg;
    for (; k + 8 <= end; k += 8) {
        unsigned p0 = packed[k + q];
        unsigned p1 = packed[k + 4 + q];
        uint4 t0 = *(const uint4*)(tab + (size_t)(p0 >> 15) * 64 + fl * 4);
        uint4 t1 = *(const uint4*)(tab + (size_t)(p1 >> 15) * 64 + fl * 4);
        float n0 = bflo(p0 & 0x7FFFu);
        float n1 = bflo(p1 & 0x7FFFu);
        EDGE_FMA(a0, n0, t0)
        EDGE_FMA(a1, n1, t1)
    }
    for (; k < end; k += 4) {
        int i0 = k + q;
        if (i0 < end) {
            unsigned p0 = packed[i0];
            uint4 t0 = *(const uint4*)(tab + (size_t)(p0 >> 15) * 64 + fl * 4);
            float n0 = bflo(p0 & 0x7FFFu);
            EDGE_FMA(a0, n0, t0)
        }
    }
#pragma unroll
    for (int j = 0; j < 8; ++j) {
        float s = a0[j] + a1[j];
        s += __shfl_xor(s, 16);
        s += __shfl_xor(s, 32);
        a0[j] = s;
    }
    if (q == 0) {
        uint4 t = *(const uint4*)(tab + (size_t)wid * 64 + fl * 4);
        EDGE_FMA(a0, dc, t)
        float4* dst = (float4*)(out + (size_t)wid * 128 + fl * 8);
        dst[0] = make_float4(a0[0], a0[1], a0[2], a0[3]);
        dst[1] = make_float4(a0[4], a0[5], a0[6], a0[7]);
    }
}

// MFMA bf16 GEMM, no W staging (wtb is L1/L2-resident): aggb (bf16) ->
// h = relu(aggb@W+b) -> aggb (bf16, in place); fused BN partial sums.
// LDS 35.8KB -> 4 blocks/CU.
__global__ __launch_bounds__(256) void k_gemm4(
        unsigned* aggb, const unsigned* __restrict__ WT,
        const float* __restrict__ bias, float* __restrict__ sums, int N) {
    __shared__ unsigned A_l[128][68];
    __shared__ float bs[256];
    int tid = threadIdx.x;
    int r0 = blockIdx.x * 128;
    bs[tid] = 0.0f;
    {
        int j = tid >> 1, h = tid & 1;
        int gr = r0 + j;
        if (gr < N) {
            const uint4* src = (const uint4*)(aggb + (size_t)gr * 64 + h * 32);
#pragma unroll
            for (int i = 0; i < 8; ++i)
                *(uint4*)&A_l[j][h * 32 + i * 4] = src[i];
        } else {
            uint4 z = {0, 0, 0, 0};
#pragma unroll
            for (int i = 0; i < 8; ++i)
                *(uint4*)&A_l[j][h * 32 + i * 4] = z;
        }
    }
    __syncthreads();

    int wv = tid >> 6, l = tid & 63;
    int lr = l & 15, lk = l >> 4;
    f32x4 acc[2][8] = {};
#pragma unroll
    for (int ks = 0; ks < 4; ++ks) {
        bf16x8 a0 = *(bf16x8*)&A_l[wv * 32 + lr][ks * 16 + lk * 4];
        bf16x8 a1 = *(bf16x8*)&A_l[wv * 32 + 16 + lr][ks * 16 + lk * 4];
#pragma unroll
        for (int nt = 0; nt < 8; ++nt) {
            bf16x8 b = *(const bf16x8*)(WT + (size_t)(nt * 16 + lr) * 64 + ks * 16 + lk * 4);
            acc[0][nt] = __builtin_amdgcn_mfma_f32_16x16x32_bf16(a0, b, acc[0][nt], 0, 0, 0);
            acc[1][nt] = __builtin_amdgcn_mfma_f32_16x16x32_bf16(a1, b, acc[1][nt], 0, 0, 0);
        }
    }

    unsigned short* ab = (unsigned short*)aggb;
#pragma unroll
    for (int nt = 0; nt < 8; ++nt) {
        int colc = nt * 16 + lr;
        float bc = bias[colc];
        float s = 0.0f, sq = 0.0f;
#pragma unroll
        for (int ms = 0; ms < 2; ++ms) {
#pragma unroll
            for (int p = 0; p < 4; ++p) {
                int rrow = r0 + wv * 32 + ms * 16 + lk * 4 + p;
                float v = fmaxf(acc[ms][nt][p] + bc, 0.0f);
                if (rrow < N) {
                    ab[(size_t)rrow * 128 + colc] = (unsigned short)bf16rn(v);
                    s += v;
                    sq += v * v;
                }
            }
        }
        s += __shfl_xor(s, 16);  s += __shfl_xor(s, 32);
        sq += __shfl_xor(sq, 16); sq += __shfl_xor(sq, 32);
        if (l < 16) {
            atomicAdd(&bs[colc], s);
            atomicAdd(&bs[128 + colc], sq);
        }
    }
    __syncthreads();
    if (tid < 128) {
        atomicAdd(&sums[tid], bs[tid]);
        atomicAdd(&sums[128 + tid], bs[128 + tid]);
    }
}

// BN finalize+apply fused: bf16 aggb -> f32 out
__global__ __launch_bounds__(256) void k_bnapplyB2(
        const unsigned* __restrict__ aggb, const float* __restrict__ sums,
        const float* __restrict__ gamma, const float* __restrict__ beta,
        float* __restrict__ out, size_t n16, int N) {
    __shared__ float sc[128], sh[128];
    int t = threadIdx.x;
    if (t < 128) {
        float inv_n = 1.0f / (float)N;
        float mean = sums[t] * inv_n;
        float var = sums[128 + t] * inv_n - mean * mean;
        float s = rsqrtf(var + 1e-5f) * gamma[t];
        sc[t] = s;
        sh[t] = beta[t] - mean * s;
    }
    __syncthreads();
    size_t i = (size_t)blockIdx.x * 256 + threadIdx.x;
    if (i >= n16) return;
    int g = (int)(i & 15);
    uint4 v = ((const uint4*)aggb)[i];
    float4 sc0 = *(float4*)&sc[g * 8];
    float4 sc1 = *(float4*)&sc[g * 8 + 4];
    float4 sh0 = *(float4*)&sh[g * 8];
    float4 sh1 = *(float4*)&sh[g * 8 + 4];
    float4 o0, o1;
    o0.x = bflo(v.x) * sc0.x + sh0.x;
    o0.y = bfhi(v.x) * sc0.y + sh0.y;
    o0.z = bflo(v.y) * sc0.z + sh0.z;
    o0.w = bfhi(v.y) * sc0.w + sh0.w;
    o1.x = bflo(v.z) * sc1.x + sh1.x;
    o1.y = bfhi(v.z) * sc1.y + sh1.y;
    o1.z = bflo(v.w) * sc1.z + sh1.z;
    o1.w = bfhi(v.w) * sc1.w + sh1.w;
    ((float4*)out)[2 * i] = o0;
    ((float4*)out)[2 * i + 1] = o1;
}

__global__ void k_bnfin(float* __restrict__ sums, const float* __restrict__ gamma,
                        const float* __restrict__ beta, int N) {
    int j = threadIdx.x;
    float inv_n = 1.0f / (float)N;
    float mean = sums[j] * inv_n;
    float var = sums[128 + j] * inv_n - mean * mean;
    float sc = rsqrtf(var + 1e-5f) * gamma[j];
    sums[256 + j] = sc;
    sums[384 + j] = beta[j] - mean * sc;
}

__global__ void k_bnapply(float* __restrict__ h, const float* __restrict__ sums, size_t n4) {
    size_t i = (size_t)blockIdx.x * 256 + threadIdx.x;
    if (i >= n4) return;
    int j4 = (int)(i & 31);
    float4 v = ((float4*)h)[i];
    float4 sc = ((const float4*)(sums + 256))[j4];
    float4 sh = ((const float4*)(sums + 384))[j4];
    v.x = v.x * sc.x + sh.x;
    v.y = v.y * sc.y + sh.y;
    v.z = v.z * sc.z + sh.z;
    v.w = v.w * sc.w + sh.w;
    ((float4*)h)[i] = v;
}

// ---------------- path 2 (reservation partition, 4B tmp format) ----------
__global__ void k_init0(int* __restrict__ bcnt, float* __restrict__ sums, int nb) {
    int i = blockIdx.x * 256 + threadIdx.x;
    if (i < nb) bcnt[i] = 0;
    if (blockIdx.x == 0 && threadIdx.x < 512) sums[threadIdx.x] = 0.0f;
}
__global__ __launch_bounds__(256) void k_bhist(const int* __restrict__ col,
                                               int* __restrict__ bcnt, int E, int nb) {
    __shared__ int h[MAX_BKT];
    for (int i = threadIdx.x; i < nb; i += 256) h[i] = 0;
    __syncthreads();
    int base = blockIdx.x * CHUNK, lim = min(base + CHUNK, E);
    for (int e = base + threadIdx.x; e < lim; e += 256)
        atomicAdd(&h[col[e] >> BKT_BITS], 1);
    __syncthreads();
    for (int i = threadIdx.x; i < nb; i += 256) {
        int c = h[i];
        if (c) atomicAdd(&bcnt[i], c);
    }
}
__global__ __launch_bounds__(1024) void k_bscan(const int* __restrict__ bcnt,
        int* __restrict__ bbase, int* __restrict__ bcur,
        int* __restrict__ ptr, int nb, int N, int E) {
    __shared__ int ls[1024];
    int t = threadIdx.x;
    int v = (t < nb) ? bcnt[t] : 0;
    ls[t] = v;
    __syncthreads();
    for (int off = 1; off < 1024; off <<= 1) {
        int u = (t >= off) ? ls[t - off] : 0;
        __syncthreads();
        ls[t] += u;
        __syncthreads();
    }
    if (t < nb) {
        int ex = ls[t] - v;
        bbase[t] = ex;
        bcur[t] = ex;
    }
    if (t == nb - 1) bbase[nb] = ls[t];
    if (t == 0) ptr[N] = E;
}
__global__ __launch_bounds__(256) void k_passA2(
        const int* __restrict__ row, const int* __restrict__ col,
        const float* __restrict__ w, int* __restrict__ bcur,
        unsigned* __restrict__ tmp, int E, int nb) {
    __shared__ int h[MAX_BKT];
    for (int i = threadIdx.x; i < nb; i += 256) h[i] = 0;
    __syncthreads();
    int base = blockIdx.x * CHUNK, lim = min(base + CHUNK, E);
    for (int e = base + threadIdx.x; e < lim; e += 256)
        atomicAdd(&h[col[e] >> BKT_BITS], 1);
    __syncthreads();
    for (int i = threadIdx.x; i < nb; i += 256) {
        int c = h[i];
        if (c) h[i] = atomicAdd(&bcur[i], c);
    }
    __syncthreads();
    for (int e = base + threadIdx.x; e < lim; e += 256) {
        int c = col[e];
        int q8 = (int)(w[e] * 256.0f + 0.5f);
        if (q8 > 255) q8 = 255;
        unsigned rec = ((unsigned)row[e] << 15) | ((unsigned)(c & 127) << 8) | (unsigned)q8;
        int pos = atomicAdd(&h[c >> BKT_BITS], 1);
        tmp[pos] = rec;
    }
}

// ---------------- path 3/4 fallbacks (full precision, independent) --------
__global__ void k_init(int* __restrict__ cnt, float* __restrict__ sums, int N) {
    int i = blockIdx.x * 256 + threadIdx.x;
    if (i < N) cnt[i] = 0;
    if (blockIdx.x == 0 && threadIdx.x < 512) sums[threadIdx.x] = 0.0f;
}
__global__ void k_count(const int* __restrict__ col, int* __restrict__ cnt, int E) {
    int e = blockIdx.x * 256 + threadIdx.x;
    if (e < E) atomicAdd(&cnt[col[e]], 1);
}
__global__ __launch_bounds__(256) void kS1(const int* __restrict__ cnt,
                                           int* __restrict__ ptr,
                                           int* __restrict__ bsum, int N) {
    __shared__ int ls[256];
    int t = threadIdx.x, i = blockIdx.x * 256 + t;
    int v = (i < N) ? cnt[i] : 0;
    ls[t] = v;
    __syncthreads();
    for (int off = 1; off < 256; off <<= 1) {
        int u = (t >= off) ? ls[t - off] : 0;
        __syncthreads();
        ls[t] += u;
        __syncthreads();
    }
    if (i < N) ptr[i] = ls[t] - v;
    if (t == 255) bsum[blockIdx.x] = ls[255];
}
__global__ __launch_bounds__(512) void kS2(int* __restrict__ bsum,
                                           int* __restrict__ ptr, int NB, int N) {
    __shared__ int ls[512];
    int t = threadIdx.x;
    int chunk = (NB + 511) / 512;
    int b = t * chunk, e = min(b + chunk, NB);
    int s = 0;
    for (int i = b; i < e; ++i) s += bsum[i];
    ls[t] = s;
    __syncthreads();
    for (int off = 1; off < 512; off <<= 1) {
        int u = (t >= off) ? ls[t - off] : 0;
        __syncthreads();
        ls[t] += u;
        __syncthreads();
    }
    int run = ls[t] - s;
    for (int i = b; i < e; ++i) { int c = bsum[i]; bsum[i] = run; run += c; }
    if (t == 511) ptr[N] = ls[511];
}
__global__ void kS3(int* __restrict__ ptr, int* __restrict__ cnt,
                    const int* __restrict__ bsum, int N) {
    int i = blockIdx.x * 256 + threadIdx.x;
    if (i >= N) return;
    int p = ptr[i] + bsum[blockIdx.x];
    ptr[i] = p;
    cnt[i] = p;
}
__global__ void k_fill(const int* __restrict__ row, const int* __restrict__ col,
                       const float* __restrict__ w, int* __restrict__ cursor,
                       int2* __restrict__ packed, int E) {
    int e = blockIdx.x * 256 + threadIdx.x;
    if (e < E) {
        int pos = atomicAdd(&cursor[col[e]], 1);
        packed[pos] = make_int2(row[e], __float_as_int(w[e]));
    }
}
__global__ __launch_bounds__(256) void k_degw(const int2* __restrict__ packed,
                                              const int* __restrict__ ptr,
                                              float* __restrict__ dinv, int N) {
    int wid = (int)(((size_t)blockIdx.x * 256 + threadIdx.x) >> 6);
    int lane = threadIdx.x & 63;
    if (wid >= N) return;
    int beg = ptr[wid], end = ptr[wid + 1];
    float s = 0.0f;
    for (int k = beg + lane; k < end; k += 64) s += __int_as_float(packed[k].y);
#pragma unroll
    for (int off = 32; off; off >>= 1) s += __shfl_xor(s, off);
    if (lane == 0) {
        float d = 1.0f + s;
        dinv[wid] = d > 0.0f ? rsqrtf(d) : 0.0f;
    }
}
__global__ __launch_bounds__(256) void k_gather(
        const int2* __restrict__ packed, const int* __restrict__ ptr,
        const float* __restrict__ dinv, const float* __restrict__ nf,
        float* __restrict__ out, int N) {
    int wid = (int)(((size_t)blockIdx.x * 256 + threadIdx.x) >> 6);
    int lane = threadIdx.x & 63;
    if (wid >= N) return;
    int c = wid;
    int beg = ptr[c], end = ptr[c + 1];
    float dc = dinv[c];
    int half = lane >> 5;
    int fl = lane & 31;
    float4 acc = {0.f, 0.f, 0.f, 0.f};
    for (int k = beg; k < end; k += 2) {
        int idx = k + half;
        bool v = idx < end;
        int2 p = packed[v ? idx : beg];
        float nrm = v ? dc * __int_as_float(p.y) * dinv[p.x] : 0.0f;
        float4 x = ((const float4*)(nf + (size_t)p.x * 128))[fl];
        acc.x += nrm * x.x; acc.y += nrm * x.y;
        acc.z += nrm * x.z; acc.w += nrm * x.w;
    }
    acc.x += __shfl_xor(acc.x, 32);
    acc.y += __shfl_xor(acc.y, 32);
    acc.z += __shfl_xor(acc.z, 32);
    acc.w += __shfl_xor(acc.w, 32);
    if (half == 0) {
        float s2 = dc * dc;
        float4 sf = ((const float4*)(nf + (size_t)c * 128))[fl];
        acc.x += s2 * sf.x; acc.y += s2 * sf.y;
        acc.z += s2 * sf.z; acc.w += s2 * sf.w;
        ((float4*)(out + (size_t)c * 128))[fl] = acc;
    }
}
__global__ void k_initA(float* __restrict__ deg, float* __restrict__ sums, int N) {
    int i = blockIdx.x * 256 + threadIdx.x;
    if (i < N) deg[i] = 1.0f;
    if (blockIdx.x == 0 && threadIdx.x < 512) sums[threadIdx.x] = 0.0f;
}
__global__ void k_deg(const int* __restrict__ col, const float* __restrict__ w,
                      float* __restrict__ deg, int E) {
    int e = blockIdx.x * 256 + threadIdx.x;
    if (e < E) atomicAdd(&deg[col[e]], w[e]);
}
__global__ void k_dinv(float* __restrict__ deg, int N) {
    int i = blockIdx.x * 256 + threadIdx.x;
    if (i < N) { float d = deg[i]; deg[i] = d > 0.0f ? rsqrtf(d) : 0.0f; }
}
__global__ void k_self(const float* __restrict__ nf, const float* __restrict__ dinv,
                       float* __restrict__ agg, int N) {
    size_t i = (size_t)blockIdx.x * 256 + threadIdx.x;
    if (i >= (size_t)N * 32) return;
    int node = (int)(i >> 5);
    float s = dinv[node]; s = s * s;
    float4 v = ((const float4*)nf)[i];
    v.x *= s; v.y *= s; v.z *= s; v.w *= s;
    ((float4*)agg)[i] = v;
}
__global__ __launch_bounds__(256) void k_scatter(
        const int* __restrict__ row, const int* __restrict__ col,
        const float* __restrict__ w, const float* __restrict__ dinv,
        const float* __restrict__ nf, float* __restrict__ agg, int E) {
    int wid = (int)(((size_t)blockIdx.x * blockDim.x + threadIdx.x) >> 6);
    int lane = threadIdx.x & 63;
    if (wid >= E) return;
    int r = row[wid], c = col[wid];
    float nrm = dinv[r] * w[wid] * dinv[c];
    float2 v = ((const float2*)(nf + (size_t)r * 128))[lane];
    float* dst = agg + (size_t)c * 128 + lane * 2;
    atomicAdd(dst, v.x * nrm);
    atomicAdd(dst + 1, v.y * nrm);
}

// legacy f32 VALU GEMM (fallback paths)
__global__ __launch_bounds__(256) void k_gemm2(float* __restrict__ h,
        const float* __restrict__ W, const float* __restrict__ bias,
        float* __restrict__ sums, int N) {
    __shared__ float At[2][32][132];
    __shared__ float Wt[2][32][132];
    int tid = threadIdx.x;
    int tx = tid & 15, ty = tid >> 4;
    int r0 = blockIdx.x * 128;
#define STAGE_A(buf, k0)                                                     \
    _Pragma("unroll")                                                        \
    for (int i = 0; i < 4; ++i) {                                            \
        int idx = tid + 256 * i;                                             \
        int row = idx >> 3, c4 = idx & 7;                                    \
        int gr = r0 + row; if (gr > N - 1) gr = N - 1;                       \
        float4 v = *(const float4*)&h[(size_t)gr * 128 + (k0) + c4 * 4];     \
        At[buf][c4 * 4 + 0][row] = v.x;                                      \
        At[buf][c4 * 4 + 1][row] = v.y;                                      \
        At[buf][c4 * 4 + 2][row] = v.z;                                      \
        At[buf][c4 * 4 + 3][row] = v.w;                                      \
    }
#define STAGE_W(buf, k0)                                                     \
    _Pragma("unroll")                                                        \
    for (int i = 0; i < 4; ++i) {                                            \
        int idx = tid + 256 * i;                                             \
        int kk = idx >> 5, c4 = idx & 31;                                    \
        float4 v = *(const float4*)&W[(size_t)((k0) + kk) * 128 + c4 * 4];   \
        *(float4*)&Wt[buf][kk][c4 * 4] = v;                                  \
    }
    STAGE_A(0, 0)
    STAGE_W(0, 0)
    float acc[8][8] = {};
    for (int t = 0; t < 4; ++t) {
        __syncthreads();
        if (t < 3) {
            int nb = (t + 1) & 1;
            STAGE_A(nb, (t + 1) * 32)
            STAGE_W(nb, (t + 1) * 32)
        }
        int kb = t & 1;
#pragma unroll
        for (int k = 0; k < 32; ++k) {
            float a[8], w[8];
            *(float4*)&a[0] = *(float4*)&At[kb][k][ty * 8];
            *(float4*)&a[4] = *(float4*)&At[kb][k][ty * 8 + 4];
            *(float4*)&w[0] = *(float4*)&Wt[kb][k][tx * 8];
            *(float4*)&w[4] = *(float4*)&Wt[kb][k][tx * 8 + 4];
#pragma unroll
            for (int r = 0; r < 8; ++r)
#pragma unroll
                for (int cc = 0; cc < 8; ++cc)
                    acc[r][cc] += a[r] * w[cc];
        }
    }
    float bv[8];
    *(float4*)&bv[0] = *(const float4*)&bias[tx * 8];
    *(float4*)&bv[4] = *(const float4*)&bias[tx * 8 + 4];
    float s[8] = {}, sq[8] = {};
#pragma unroll
    for (int r = 0; r < 8; ++r) {
        int gr = r0 + ty * 8 + r;
        if (gr < N) {
            float o[8];
#pragma unroll
            for (int cc = 0; cc < 8; ++cc) {
                o[cc] = fmaxf(acc[r][cc] + bv[cc], 0.0f);
                s[cc] += o[cc];
                sq[cc] += o[cc] * o[cc];
            }
            float4* dst = (float4*)&h[(size_t)gr * 128 + tx * 8];
            dst[0] = make_float4(o[0], o[1], o[2], o[3]);
            dst[1] = make_float4(o[4], o[5], o[6], o[7]);
        }
    }
    float* ls = &At[0][0][0];
    __syncthreads();
#pragma unroll
    for (int cc = 0; cc < 8; ++cc) {
        ls[ty * 128 + tx * 8 + cc] = s[cc];
        ls[2048 + ty * 128 + tx * 8 + cc] = sq[cc];
    }
    __syncthreads();
    if (tid < 128) {
        float ssum = 0.f, sqsum = 0.f;
#pragma unroll
        for (int u = 0; u < 16; ++u) {
            ssum += ls[u * 128 + tid];
            sqsum += ls[2048 + u * 128 + tid];
        }
        atomicAdd(&sums[tid], ssum);
        atomicAdd(&sums[128 + tid], sqsum);
    }
#undef STAGE_A
#undef STAGE_W
}

extern "C" void kernel_launch(void* const* d_in, const int* in_sizes, int n_in,
                              void* d_out, int out_size, void* d_ws, size_t ws_size,
                              hipStream_t stream) {
    const float* nf    = (const float*)d_in[0];
    const int*   ei    = (const int*)d_in[1];
    const float* ew    = (const float*)d_in[2];
    const float* W     = (const float*)d_in[3];
    const float* bias  = (const float*)d_in[4];
    const float* gamma = (const float*)d_in[5];
    const float* beta  = (const float*)d_in[6];
    float* out = (float*)d_out;

    const int N = in_sizes[0] / 128;
    const int E = in_sizes[2];
    const int* row = ei;
    const int* col = ei + E;

    int nb_n  = (N + 255) / 256;
    int nb_e  = (E + 255) / 256;
    int nb_w  = (int)(((size_t)N + 3) / 4);
    int nb_v4 = (int)(((size_t)N * 32 + 255) / 256);
    int nbk   = (N + BKT_SZ - 1) >> BKT_BITS;
    int nb_c  = (E + CHUNK - 1) / CHUNK;
    int nconv = (int)(((size_t)N * 16 + 255) / 256);
    size_t n16 = (size_t)N * 16;
    size_t tt_words = (size_t)64 * N > (size_t)E ? (size_t)64 * N : (size_t)E;

    // ---- path-1 layout ----
    float* dinv = (float*)d_ws;                  // N
    int*   ptr  = (int*)d_ws + N;                // N+1
    float* sums = (float*)d_ws + 2 * N + 1;      // 512
    int*   bbase1 = (int*)d_ws + 2 * N + 513;    // nbk+1
    int*   btot   = bbase1 + nbk + 1;            // nbk (unused, kept for layout)
    int*   blkoff = btot + nbk;                  // nbk*nb_c
    size_t wt_off = ((size_t)(2 * N + 514 + 2 * nbk) + (size_t)nbk * nb_c + 3) & ~(size_t)3;
    unsigned* wtb = (unsigned*)((int*)d_ws + wt_off);             // 8192
    size_t pk_off = (wt_off + 8192 + 3) & ~(size_t)3;
    unsigned* p1_packed = (unsigned*)((int*)d_ws + pk_off);       // E
    size_t tt_off = (pk_off + (size_t)E + 3) & ~(size_t)3;
    unsigned* p1_tmp = (unsigned*)((int*)d_ws + tt_off);          // tmp(E)/tab(64N)
    unsigned* p1_tab = (unsigned*)((int*)d_ws + tt_off);
    size_t ab_off = (tt_off + tt_words + 3) & ~(size_t)3;
    unsigned* aggb = (unsigned*)((int*)d_ws + ab_off);            // 64N
    size_t need_p1 = (ab_off + (size_t)64 * N) * 4;

    // ---- path-2 layout (4B tmp format) ----
    float* dinv2 = (float*)d_ws;
    int*   ptr2  = (int*)d_ws + N;
    int*   cnt3  = (int*)d_ws + 2 * N + 1;
    float* sums2 = (float*)d_ws + 3 * N + 1;
    int*   bsum2 = (int*)d_ws + 3 * N + 513;
    int*   bbase2 = (int*)d_ws + 3 * N + 1025;
    int*   bcur2  = bbase2 + nbk + 1;
    size_t pk2 = ((size_t)(3 * N + 1026 + 2 * nbk) + 3) & ~(size_t)3;
    unsigned* packed2 = (unsigned*)((int*)d_ws + pk2);            // E
    size_t tt2 = (pk2 + (size_t)E + 3) & ~(size_t)3;
    unsigned* tmp2 = (unsigned*)((int*)d_ws + tt2);
    unsigned* tab2 = (unsigned*)((int*)d_ws + tt2);
    size_t need_full2 = (tt2 + tt_words) * 4;

    // ---- path-3 layout (int2 packed, f32 gather) ----
    int2*  packed3 = (int2*)((int*)d_ws + pk2);                   // 2E
    size_t need_csr3 = (pk2 + (size_t)2 * E) * 4;

    if (nbk <= MAX_BKT && ws_size >= need_p1) {
        k_bhist2<<<nb_c, 256, 0, stream>>>(col, blkoff, W, wtb, E, nbk, nb_c);
        k_bscanM<<<1, 1024, 0, stream>>>(blkoff, bbase1, ptr, sums, nbk, nb_c, N, E);
        k_passA3<<<nb_c, 256, 0, stream>>>(row, col, ew, blkoff, bbase1, p1_tmp, E, nbk, nb_c);
        k_passB2<<<nbk, 256, 0, stream>>>(p1_tmp, bbase1, p1_packed, ptr, dinv, N);
        k_conv2<<<nconv, 256, 0, stream>>>(nf, dinv, (uint4*)p1_tab, N);
        k_gatherw5<<<nb_w, 256, 0, stream>>>(p1_packed, ptr, dinv, p1_tab, aggb, N);
        k_gemm4<<<(N + 127) / 128, 256, 0, stream>>>(aggb, wtb, bias, sums, N);
        k_bnapplyB2<<<(int)((n16 + 255) / 256), 256, 0, stream>>>(aggb, sums, gamma, beta, out, n16, N);
        return;
    }

    if (nbk <= MAX_BKT && ws_size >= need_full2) {
        k_init0<<<(max(nbk, 512) + 255) / 256, 256, 0, stream>>>(bcur2, sums2, nbk);
        k_bhist<<<nb_c, 256, 0, stream>>>(col, bcur2, E, nbk);
        k_bscan<<<1, 1024, 0, stream>>>(bcur2, bbase2, bcur2, ptr2, nbk, N, E);
        k_passA2<<<nb_c, 256, 0, stream>>>(row, col, ew, bcur2, tmp2, E, nbk);
        k_passB2<<<nbk, 256, 0, stream>>>(tmp2, bbase2, packed2, ptr2, dinv2, N);
        k_conv2<<<nconv, 256, 0, stream>>>(nf, dinv2, (uint4*)tab2, N);
        k_gatherwF<<<nb_w, 256, 0, stream>>>(packed2, ptr2, dinv2, tab2, out, N);
        k_gemm2<<<(N + 127) / 128, 256, 0, stream>>>(out, W, bias, sums2, N);
        k_bnfin<<<1, 128, 0, stream>>>(sums2, gamma, beta, N);
        k_bnapply<<<nb_v4, 256, 0, stream>>>(out, sums2, (size_t)N * 32);
        return;
    }

    if (ws_size >= need_csr3) {
        k_init<<<nb_n, 256, 0, stream>>>(cnt3, sums2, N);
        k_count<<<nb_e, 256, 0, stream>>>(col, cnt3, E);
        kS1<<<nb_n, 256, 0, stream>>>(cnt3, ptr2, bsum2, N);
        kS2<<<1, 512, 0, stream>>>(bsum2, ptr2, nb_n, N);
        kS3<<<nb_n, 256, 0, stream>>>(ptr2, cnt3, bsum2, N);
        k_fill<<<nb_e, 256, 0, stream>>>(row, col, ew, cnt3, packed3, E);
        k_degw<<<nb_w, 256, 0, stream>>>(packed3, ptr2, dinv2, N);
        k_gather<<<nb_w, 256, 0, stream>>>(packed3, ptr2, dinv2, nf, out, N);
        k_gemm2<<<(N + 127) / 128, 256, 0, stream>>>(out, W, bias, sums2, N);
        k_bnfin<<<1, 128, 0, stream>>>(sums2, gamma, beta, N);
        k_bnapply<<<nb_v4, 256, 0, stream>>>(out, sums2, (size_t)N * 32);
        return;
    }

    {
        float* deg = (float*)d_ws;
        float* sm  = (float*)d_ws + N;
        k_initA<<<nb_n, 256, 0, stream>>>(deg, sm, N);
        k_deg<<<nb_e, 256, 0, stream>>>(col, ew, deg, E);
        k_dinv<<<nb_n, 256, 0, stream>>>(deg, N);
        k_self<<<nb_v4, 256, 0, stream>>>(nf, deg, out, N);
        k_scatter<<<(E + 3) / 4, 256, 0, stream>>>(row, col, ew, deg, nf, out, E);
        k_gemm2<<<(N + 127) / 128, 256, 0, stream>>>(out, W, bias, sm, N);
        k_bnfin<<<1, 128, 0, stream>>>(sm, gamma, beta, N);
        k_bnapply<<<nb_v4, 256, 0, stream>>>(out, sm, (size_t)N * 32);
    }
}

// Round 12
// 339.116 us; speedup vs baseline: 2.5122x; 2.5122x over previous
//
#include <hip/hip_runtime.h>
#include <hip/hip_bf16.h>

// GCN layer: h = BN(ReLU(segment_sum(norm * (nf@W))[col] + b))
// R1: CSR gather.  R2: bf16 table.  R4: block-reservation radix partition.
// R5: fold dinv into tab.  R6: MFMA bf16 GEMM, bf16 h.
// R8: zero-waste wave-per-node gather (107us; R7/R9 restructures regressed
//     -> gather is at the ~3.5TB/s random-256B fabric ceiling).
// R10: gemm4 (no W LDS stage -> 4 blocks/CU).
// R11: REVERT merged scan (single-block serial walk of blkoff = 589us!)
//      back to split k_bscan2a (multi-block, parallel over buckets) +
//      k_bscan2b (single-block totals scan). Everything else kept.

#define BKT_BITS 7
#define BKT_SZ 128
#define MAX_BKT 1024        // N <= 131072 (row fits 17 bits)
#define CHUNK 8192

typedef __attribute__((ext_vector_type(8))) short bf16x8;
typedef __attribute__((ext_vector_type(4))) float f32x4;

__device__ __forceinline__ unsigned bf16rn(float f) {
    unsigned x = __float_as_uint(f);
    return (x + 0x7fffu + ((x >> 16) & 1u)) >> 16;
}
__device__ __forceinline__ float bflo(unsigned u) { return __uint_as_float(u << 16); }
__device__ __forceinline__ float bfhi(unsigned u) { return __uint_as_float(u & 0xffff0000u); }

// ---------------- path 1: single-histogram radix partition ----------------
// + convW folded into block 0
__global__ __launch_bounds__(256) void k_bhist2(const int* __restrict__ col,
        int* __restrict__ blkoff, const float* __restrict__ Wm,
        unsigned* __restrict__ WT, int E, int nb, int nbc) {
    __shared__ int h[MAX_BKT];
    for (int i = threadIdx.x; i < nb; i += 256) h[i] = 0;
    __syncthreads();
    int base = blockIdx.x * CHUNK, lim = min(base + CHUNK, E);
    for (int e = base + threadIdx.x; e < lim; e += 256)
        atomicAdd(&h[col[e] >> BKT_BITS], 1);
    __syncthreads();
    for (int i = threadIdx.x; i < nb; i += 256)
        blkoff[(size_t)i * nbc + blockIdx.x] = h[i];
    if (blockIdx.x == 0) {
        // WT[j][k2] = bf16(W[2k2][j]) | bf16(W[2k2+1][j])<<16
        for (int i = threadIdx.x; i < 128 * 64; i += 256) {
            int j = i >> 6, w = i & 63;
            float a = Wm[(size_t)(2 * w) * 128 + j];
            float b = Wm[(size_t)(2 * w + 1) * 128 + j];
            WT[i] = bf16rn(a) | (bf16rn(b) << 16);
        }
    }
}

// per-bucket exclusive scan over blocks (one thread per bucket, multi-block)
__global__ void k_bscan2a(int* __restrict__ blkoff, int* __restrict__ btot,
                          int nb, int nbc) {
    int b = blockIdx.x * 256 + threadIdx.x;
    if (b >= nb) return;
    int* p = blkoff + (size_t)b * nbc;
    int run = 0;
#pragma unroll 4
    for (int i = 0; i < nbc; ++i) { int c = p[i]; p[i] = run; run += c; }
    btot[b] = run;
}

// scan bucket totals -> bbase; also ptr[N]=E and zero BN sums
__global__ __launch_bounds__(1024) void k_bscan2b(const int* __restrict__ btot,
        int* __restrict__ bbase, int* __restrict__ ptr, float* __restrict__ sums,
        int nb, int N, int E) {
    __shared__ int ls[1024];
    int t = threadIdx.x;
    int v = (t < nb) ? btot[t] : 0;
    ls[t] = v;
    __syncthreads();
    for (int off = 1; off < 1024; off <<= 1) {
        int u = (t >= off) ? ls[t - off] : 0;
        __syncthreads();
        ls[t] += u;
        __syncthreads();
    }
    if (t < nb) bbase[t] = ls[t] - v;
    if (t == nb - 1) bbase[nb] = ls[t];
    if (t == 0) ptr[N] = E;
    if (t < 512) sums[t] = 0.0f;
}

// scatter into bucket-grouped tmp: rec = row17<<15 | col7<<8 | w8
__global__ __launch_bounds__(256) void k_passA3(
        const int* __restrict__ row, const int* __restrict__ col,
        const float* __restrict__ w, const int* __restrict__ blkoff,
        const int* __restrict__ bbase, unsigned* __restrict__ tmp,
        int E, int nb, int nbc) {
    __shared__ int cur[MAX_BKT];
    for (int i = threadIdx.x; i < nb; i += 256)
        cur[i] = bbase[i] + blkoff[(size_t)i * nbc + blockIdx.x];
    __syncthreads();
    int base = blockIdx.x * CHUNK, lim = min(base + CHUNK, E);
    for (int e = base + threadIdx.x; e < lim; e += 256) {
        int c = col[e];
        int q8 = (int)(w[e] * 256.0f + 0.5f);
        if (q8 > 255) q8 = 255;
        unsigned rec = ((unsigned)row[e] << 15) | ((unsigned)(c & 127) << 8) | (unsigned)q8;
        int pos = atomicAdd(&cur[c >> BKT_BITS], 1);
        tmp[pos] = rec;
    }
}

// pass B: per-node offsets in LDS, place edges as row17|wbf15
// (wbf15 = bf16 bits of w*dinv[col], <0x8000), fused degree -> dinv.
__global__ __launch_bounds__(256) void k_passB2(
        const unsigned* __restrict__ tmp, const int* __restrict__ bbase,
        unsigned* __restrict__ packed, int* __restrict__ ptr,
        float* __restrict__ dinv, int N) {
    __shared__ int hcnt[BKT_SZ];
    __shared__ int wsumi[BKT_SZ];
    __shared__ int cur[BKT_SZ];
    __shared__ float dcl[BKT_SZ];
    int b = blockIdx.x;
    int t = threadIdx.x;
    if (t < BKT_SZ) { hcnt[t] = 0; wsumi[t] = 0; }
    __syncthreads();
    int beg = bbase[b], end = bbase[b + 1];
    for (int k = beg + t; k < end; k += 256) {
        unsigned p = tmp[k];
        int li = (p >> 8) & 127;
        atomicAdd(&hcnt[li], 1);
        atomicAdd(&wsumi[li], (int)(p & 255u));
    }
    __syncthreads();
    if (t < BKT_SZ) cur[t] = hcnt[t];
    __syncthreads();
    for (int off = 1; off < BKT_SZ; off <<= 1) {
        int v = (t < BKT_SZ && t >= off) ? cur[t - off] : 0;
        __syncthreads();
        if (t < BKT_SZ) cur[t] += v;
        __syncthreads();
    }
    if (t < BKT_SZ) {
        int p = beg + cur[t] - hcnt[t];
        cur[t] = p;
        float d = 1.0f + (float)wsumi[t] * (1.0f / 256.0f);
        float dc = rsqrtf(d);
        dcl[t] = dc;
        int n = (b << BKT_BITS) + t;
        if (n < N) { ptr[n] = p; dinv[n] = dc; }
    }
    __syncthreads();
    for (int k = beg + t; k < end; k += 256) {
        unsigned p = tmp[k];
        int li = (p >> 8) & 127;
        int pos = atomicAdd(&cur[li], 1);
        float fw = (float)(p & 255u) * (1.0f / 256.0f) * dcl[li];
        unsigned wb = bf16rn(fw) & 0x7FFFu;
        packed[pos] = ((p >> 15) << 15) | wb;
    }
}

// tab[r] = bf16(nf[r] * dinv[r])
__global__ void k_conv2(const float* __restrict__ nf, const float* __restrict__ dinv,
                        uint4* __restrict__ tab, int N) {
    size_t i = (size_t)blockIdx.x * 256 + threadIdx.x;
    if (i >= (size_t)N * 16) return;
    int n = (int)(i >> 4);
    float dv = dinv[n];
    const float4* src = (const float4*)nf + 2 * i;
    float4 a = src[0], b = src[1];
    uint4 r;
    r.x = bf16rn(a.x * dv) | (bf16rn(a.y * dv) << 16);
    r.y = bf16rn(a.z * dv) | (bf16rn(a.w * dv) << 16);
    r.z = bf16rn(b.x * dv) | (bf16rn(b.y * dv) << 16);
    r.w = bf16rn(b.z * dv) | (bf16rn(b.w * dv) << 16);
    tab[i] = r;
}

#define EDGE_FMA(aX, nX, tX)                                     \
    aX[0] += nX * bflo(tX.x); aX[1] += nX * bfhi(tX.x);          \
    aX[2] += nX * bflo(tX.y); aX[3] += nX * bfhi(tX.y);          \
    aX[4] += nX * bflo(tX.z); aX[5] += nX * bfhi(tX.z);          \
    aX[6] += nX * bflo(tX.w); aX[7] += nX * bfhi(tX.w);

// gather (R8 structure): wave per node; uncond 4-deep main, 2-deep mid,
// exec-masked tail. rec = row17|wbf15; dinv[row] folded in tab.
__global__ __launch_bounds__(256) void k_gatherw5(
        const unsigned* __restrict__ packed, const int* __restrict__ ptr,
        const float* __restrict__ dinv, const unsigned* __restrict__ tab,
        unsigned* __restrict__ aggb, int N) {
    int wid = (int)(((size_t)blockIdx.x * 256 + threadIdx.x) >> 6);
    int lane = threadIdx.x & 63;
    if (wid >= N) return;
    int beg = ptr[wid], end = ptr[wid + 1];
    float dc = dinv[wid];
    int q = lane >> 4;       // edge slot
    int fl = lane & 15;      // features [8*fl, 8*fl+8)
    float a0[8] = {}, a1[8] = {}, a2[8] = {}, a3[8] = {};
    int k = beg;
    for (; k + 16 <= end; k += 16) {
        unsigned p0 = packed[k + q];
        unsigned p1 = packed[k + 4 + q];
        unsigned p2 = packed[k + 8 + q];
        unsigned p3 = packed[k + 12 + q];
        uint4 t0 = *(const uint4*)(tab + (size_t)(p0 >> 15) * 64 + fl * 4);
        uint4 t1 = *(const uint4*)(tab + (size_t)(p1 >> 15) * 64 + fl * 4);
        uint4 t2 = *(const uint4*)(tab + (size_t)(p2 >> 15) * 64 + fl * 4);
        uint4 t3 = *(const uint4*)(tab + (size_t)(p3 >> 15) * 64 + fl * 4);
        float n0 = bflo(p0 & 0x7FFFu);
        float n1 = bflo(p1 & 0x7FFFu);
        float n2 = bflo(p2 & 0x7FFFu);
        float n3 = bflo(p3 & 0x7FFFu);
        EDGE_FMA(a0, n0, t0)
        EDGE_FMA(a1, n1, t1)
        EDGE_FMA(a2, n2, t2)
        EDGE_FMA(a3, n3, t3)
    }
    if (k + 8 <= end) {
        unsigned p0 = packed[k + q];
        unsigned p1 = packed[k + 4 + q];
        uint4 t0 = *(const uint4*)(tab + (size_t)(p0 >> 15) * 64 + fl * 4);
        uint4 t1 = *(const uint4*)(tab + (size_t)(p1 >> 15) * 64 + fl * 4);
        float n0 = bflo(p0 & 0x7FFFu);
        float n1 = bflo(p1 & 0x7FFFu);
        EDGE_FMA(a0, n0, t0)
        EDGE_FMA(a1, n1, t1)
        k += 8;
    }
    for (; k < end; k += 4) {
        int i0 = k + q;
        if (i0 < end) {      // exec-masked: no loads from invalid lanes
            unsigned p0 = packed[i0];
            uint4 t0 = *(const uint4*)(tab + (size_t)(p0 >> 15) * 64 + fl * 4);
            float n0 = bflo(p0 & 0x7FFFu);
            EDGE_FMA(a0, n0, t0)
        }
    }
#pragma unroll
    for (int j = 0; j < 8; ++j) {
        float s = (a0[j] + a1[j]) + (a2[j] + a3[j]);
        s += __shfl_xor(s, 16);
        s += __shfl_xor(s, 32);
        a0[j] = s;
    }
    if (q == 0) {
        uint4 t = *(const uint4*)(tab + (size_t)wid * 64 + fl * 4);
        EDGE_FMA(a0, dc, t)   // self: dc*tab[c]
        uint4 r;
        r.x = bf16rn(a0[0]) | (bf16rn(a0[1]) << 16);
        r.y = bf16rn(a0[2]) | (bf16rn(a0[3]) << 16);
        r.z = bf16rn(a0[4]) | (bf16rn(a0[5]) << 16);
        r.w = bf16rn(a0[6]) | (bf16rn(a0[7]) << 16);
        *(uint4*)(aggb + (size_t)wid * 64 + fl * 4) = r;
    }
}

// gather -> f32 rows into out (path-2 fallback; same packed format)
__global__ __launch_bounds__(256) void k_gatherwF(
        const unsigned* __restrict__ packed, const int* __restrict__ ptr,
        const float* __restrict__ dinv, const unsigned* __restrict__ tab,
        float* __restrict__ out, int N) {
    int wid = (int)(((size_t)blockIdx.x * 256 + threadIdx.x) >> 6);
    int lane = threadIdx.x & 63;
    if (wid >= N) return;
    int beg = ptr[wid], end = ptr[wid + 1];
    float dc = dinv[wid];
    int q = lane >> 4;
    int fl = lane & 15;
    float a0[8] = {}, a1[8] = {};
    int k = beg;
    for (; k + 8 <= end; k += 8) {
        unsigned p0 = packed[k + q];
        unsigned p1 = packed[k + 4 + q];
        uint4 t0 = *(const uint4*)(tab + (size_t)(p0 >> 15) * 64 + fl * 4);
        uint4 t1 = *(const uint4*)(tab + (size_t)(p1 >> 15) * 64 + fl * 4);
        float n0 = bflo(p0 & 0x7FFFu);
        float n1 = bflo(p1 & 0x7FFFu);
        EDGE_FMA(a0, n0, t0)
        EDGE_FMA(a1, n1, t1)
    }
    for (; k < end; k += 4) {
        int i0 = k + q;
        if (i0 < end) {
            unsigned p0 = packed[i0];
            uint4 t0 = *(const uint4*)(tab + (size_t)(p0 >> 15) * 64 + fl * 4);
            float n0 = bflo(p0 & 0x7FFFu);
            EDGE_FMA(a0, n0, t0)
        }
    }
#pragma unroll
    for (int j = 0; j < 8; ++j) {
        float s = a0[j] + a1[j];
        s += __shfl_xor(s, 16);
        s += __shfl_xor(s, 32);
        a0[j] = s;
    }
    if (q == 0) {
        uint4 t = *(const uint4*)(tab + (size_t)wid * 64 + fl * 4);
        EDGE_FMA(a0, dc, t)
        float4* dst = (float4*)(out + (size_t)wid * 128 + fl * 8);
        dst[0] = make_float4(a0[0], a0[1], a0[2], a0[3]);
        dst[1] = make_float4(a0[4], a0[5], a0[6], a0[7]);
    }
}

// MFMA bf16 GEMM, no W staging (wtb is L1/L2-resident): aggb (bf16) ->
// h = relu(aggb@W+b) -> aggb (bf16, in place); fused BN partial sums.
// LDS 35.8KB -> 4 blocks/CU.
__global__ __launch_bounds__(256) void k_gemm4(
        unsigned* aggb, const unsigned* __restrict__ WT,
        const float* __restrict__ bias, float* __restrict__ sums, int N) {
    __shared__ unsigned A_l[128][68];
    __shared__ float bs[256];
    int tid = threadIdx.x;
    int r0 = blockIdx.x * 128;
    bs[tid] = 0.0f;
    {
        int j = tid >> 1, h = tid & 1;
        int gr = r0 + j;
        if (gr < N) {
            const uint4* src = (const uint4*)(aggb + (size_t)gr * 64 + h * 32);
#pragma unroll
            for (int i = 0; i < 8; ++i)
                *(uint4*)&A_l[j][h * 32 + i * 4] = src[i];
        } else {
            uint4 z = {0, 0, 0, 0};
#pragma unroll
            for (int i = 0; i < 8; ++i)
                *(uint4*)&A_l[j][h * 32 + i * 4] = z;
        }
    }
    __syncthreads();

    int wv = tid >> 6, l = tid & 63;
    int lr = l & 15, lk = l >> 4;
    f32x4 acc[2][8] = {};
#pragma unroll
    for (int ks = 0; ks < 4; ++ks) {
        bf16x8 a0 = *(bf16x8*)&A_l[wv * 32 + lr][ks * 16 + lk * 4];
        bf16x8 a1 = *(bf16x8*)&A_l[wv * 32 + 16 + lr][ks * 16 + lk * 4];
#pragma unroll
        for (int nt = 0; nt < 8; ++nt) {
            bf16x8 b = *(const bf16x8*)(WT + (size_t)(nt * 16 + lr) * 64 + ks * 16 + lk * 4);
            acc[0][nt] = __builtin_amdgcn_mfma_f32_16x16x32_bf16(a0, b, acc[0][nt], 0, 0, 0);
            acc[1][nt] = __builtin_amdgcn_mfma_f32_16x16x32_bf16(a1, b, acc[1][nt], 0, 0, 0);
        }
    }

    unsigned short* ab = (unsigned short*)aggb;
#pragma unroll
    for (int nt = 0; nt < 8; ++nt) {
        int colc = nt * 16 + lr;
        float bc = bias[colc];
        float s = 0.0f, sq = 0.0f;
#pragma unroll
        for (int ms = 0; ms < 2; ++ms) {
#pragma unroll
            for (int p = 0; p < 4; ++p) {
                int rrow = r0 + wv * 32 + ms * 16 + lk * 4 + p;
                float v = fmaxf(acc[ms][nt][p] + bc, 0.0f);
                if (rrow < N) {
                    ab[(size_t)rrow * 128 + colc] = (unsigned short)bf16rn(v);
                    s += v;
                    sq += v * v;
                }
            }
        }
        s += __shfl_xor(s, 16);  s += __shfl_xor(s, 32);
        sq += __shfl_xor(sq, 16); sq += __shfl_xor(sq, 32);
        if (l < 16) {
            atomicAdd(&bs[colc], s);
            atomicAdd(&bs[128 + colc], sq);
        }
    }
    __syncthreads();
    if (tid < 128) {
        atomicAdd(&sums[tid], bs[tid]);
        atomicAdd(&sums[128 + tid], bs[128 + tid]);
    }
}

// BN finalize+apply fused: bf16 aggb -> f32 out
__global__ __launch_bounds__(256) void k_bnapplyB2(
        const unsigned* __restrict__ aggb, const float* __restrict__ sums,
        const float* __restrict__ gamma, const float* __restrict__ beta,
        float* __restrict__ out, size_t n16, int N) {
    __shared__ float sc[128], sh[128];
    int t = threadIdx.x;
    if (t < 128) {
        float inv_n = 1.0f / (float)N;
        float mean = sums[t] * inv_n;
        float var = sums[128 + t] * inv_n - mean * mean;
        float s = rsqrtf(var + 1e-5f) * gamma[t];
        sc[t] = s;
        sh[t] = beta[t] - mean * s;
    }
    __syncthreads();
    size_t i = (size_t)blockIdx.x * 256 + threadIdx.x;
    if (i >= n16) return;
    int g = (int)(i & 15);
    uint4 v = ((const uint4*)aggb)[i];
    float4 sc0 = *(float4*)&sc[g * 8];
    float4 sc1 = *(float4*)&sc[g * 8 + 4];
    float4 sh0 = *(float4*)&sh[g * 8];
    float4 sh1 = *(float4*)&sh[g * 8 + 4];
    float4 o0, o1;
    o0.x = bflo(v.x) * sc0.x + sh0.x;
    o0.y = bfhi(v.x) * sc0.y + sh0.y;
    o0.z = bflo(v.y) * sc0.z + sh0.z;
    o0.w = bfhi(v.y) * sc0.w + sh0.w;
    o1.x = bflo(v.z) * sc1.x + sh1.x;
    o1.y = bfhi(v.z) * sc1.y + sh1.y;
    o1.z = bflo(v.w) * sc1.z + sh1.z;
    o1.w = bfhi(v.w) * sc1.w + sh1.w;
    ((float4*)out)[2 * i] = o0;
    ((float4*)out)[2 * i + 1] = o1;
}

__global__ void k_bnfin(float* __restrict__ sums, const float* __restrict__ gamma,
                        const float* __restrict__ beta, int N) {
    int j = threadIdx.x;
    float inv_n = 1.0f / (float)N;
    float mean = sums[j] * inv_n;
    float var = sums[128 + j] * inv_n - mean * mean;
    float sc = rsqrtf(var + 1e-5f) * gamma[j];
    sums[256 + j] = sc;
    sums[384 + j] = beta[j] - mean * sc;
}

__global__ void k_bnapply(float* __restrict__ h, const float* __restrict__ sums, size_t n4) {
    size_t i = (size_t)blockIdx.x * 256 + threadIdx.x;
    if (i >= n4) return;
    int j4 = (int)(i & 31);
    float4 v = ((float4*)h)[i];
    float4 sc = ((const float4*)(sums + 256))[j4];
    float4 sh = ((const float4*)(sums + 384))[j4];
    v.x = v.x * sc.x + sh.x;
    v.y = v.y * sc.y + sh.y;
    v.z = v.z * sc.z + sh.z;
    v.w = v.w * sc.w + sh.w;
    ((float4*)h)[i] = v;
}

// ---------------- path 2 (reservation partition, 4B tmp format) ----------
__global__ void k_init0(int* __restrict__ bcnt, float* __restrict__ sums, int nb) {
    int i = blockIdx.x * 256 + threadIdx.x;
    if (i < nb) bcnt[i] = 0;
    if (blockIdx.x == 0 && threadIdx.x < 512) sums[threadIdx.x] = 0.0f;
}
__global__ __launch_bounds__(256) void k_bhist(const int* __restrict__ col,
                                               int* __restrict__ bcnt, int E, int nb) {
    __shared__ int h[MAX_BKT];
    for (int i = threadIdx.x; i < nb; i += 256) h[i] = 0;
    __syncthreads();
    int base = blockIdx.x * CHUNK, lim = min(base + CHUNK, E);
    for (int e = base + threadIdx.x; e < lim; e += 256)
        atomicAdd(&h[col[e] >> BKT_BITS], 1);
    __syncthreads();
    for (int i = threadIdx.x; i < nb; i += 256) {
        int c = h[i];
        if (c) atomicAdd(&bcnt[i], c);
    }
}
__global__ __launch_bounds__(1024) void k_bscan(const int* __restrict__ bcnt,
        int* __restrict__ bbase, int* __restrict__ bcur,
        int* __restrict__ ptr, int nb, int N, int E) {
    __shared__ int ls[1024];
    int t = threadIdx.x;
    int v = (t < nb) ? bcnt[t] : 0;
    ls[t] = v;
    __syncthreads();
    for (int off = 1; off < 1024; off <<= 1) {
        int u = (t >= off) ? ls[t - off] : 0;
        __syncthreads();
        ls[t] += u;
        __syncthreads();
    }
    if (t < nb) {
        int ex = ls[t] - v;
        bbase[t] = ex;
        bcur[t] = ex;
    }
    if (t == nb - 1) bbase[nb] = ls[t];
    if (t == 0) ptr[N] = E;
}
__global__ __launch_bounds__(256) void k_passA2(
        const int* __restrict__ row, const int* __restrict__ col,
        const float* __restrict__ w, int* __restrict__ bcur,
        unsigned* __restrict__ tmp, int E, int nb) {
    __shared__ int h[MAX_BKT];
    for (int i = threadIdx.x; i < nb; i += 256) h[i] = 0;
    __syncthreads();
    int base = blockIdx.x * CHUNK, lim = min(base + CHUNK, E);
    for (int e = base + threadIdx.x; e < lim; e += 256)
        atomicAdd(&h[col[e] >> BKT_BITS], 1);
    __syncthreads();
    for (int i = threadIdx.x; i < nb; i += 256) {
        int c = h[i];
        if (c) h[i] = atomicAdd(&bcur[i], c);
    }
    __syncthreads();
    for (int e = base + threadIdx.x; e < lim; e += 256) {
        int c = col[e];
        int q8 = (int)(w[e] * 256.0f + 0.5f);
        if (q8 > 255) q8 = 255;
        unsigned rec = ((unsigned)row[e] << 15) | ((unsigned)(c & 127) << 8) | (unsigned)q8;
        int pos = atomicAdd(&h[c >> BKT_BITS], 1);
        tmp[pos] = rec;
    }
}

// ---------------- path 3/4 fallbacks (full precision, independent) --------
__global__ void k_init(int* __restrict__ cnt, float* __restrict__ sums, int N) {
    int i = blockIdx.x * 256 + threadIdx.x;
    if (i < N) cnt[i] = 0;
    if (blockIdx.x == 0 && threadIdx.x < 512) sums[threadIdx.x] = 0.0f;
}
__global__ void k_count(const int* __restrict__ col, int* __restrict__ cnt, int E) {
    int e = blockIdx.x * 256 + threadIdx.x;
    if (e < E) atomicAdd(&cnt[col[e]], 1);
}
__global__ __launch_bounds__(256) void kS1(const int* __restrict__ cnt,
                                           int* __restrict__ ptr,
                                           int* __restrict__ bsum, int N) {
    __shared__ int ls[256];
    int t = threadIdx.x, i = blockIdx.x * 256 + t;
    int v = (i < N) ? cnt[i] : 0;
    ls[t] = v;
    __syncthreads();
    for (int off = 1; off < 256; off <<= 1) {
        int u = (t >= off) ? ls[t - off] : 0;
        __syncthreads();
        ls[t] += u;
        __syncthreads();
    }
    if (i < N) ptr[i] = ls[t] - v;
    if (t == 255) bsum[blockIdx.x] = ls[255];
}
__global__ __launch_bounds__(512) void kS2(int* __restrict__ bsum,
                                           int* __restrict__ ptr, int NB, int N) {
    __shared__ int ls[512];
    int t = threadIdx.x;
    int chunk = (NB + 511) / 512;
    int b = t * chunk, e = min(b + chunk, NB);
    int s = 0;
    for (int i = b; i < e; ++i) s += bsum[i];
    ls[t] = s;
    __syncthreads();
    for (int off = 1; off < 512; off <<= 1) {
        int u = (t >= off) ? ls[t - off] : 0;
        __syncthreads();
        ls[t] += u;
        __syncthreads();
    }
    int run = ls[t] - s;
    for (int i = b; i < e; ++i) { int c = bsum[i]; bsum[i] = run; run += c; }
    if (t == 511) ptr[N] = ls[511];
}
__global__ void kS3(int* __restrict__ ptr, int* __restrict__ cnt,
                    const int* __restrict__ bsum, int N) {
    int i = blockIdx.x * 256 + threadIdx.x;
    if (i >= N) return;
    int p = ptr[i] + bsum[blockIdx.x];
    ptr[i] = p;
    cnt[i] = p;
}
__global__ void k_fill(const int* __restrict__ row, const int* __restrict__ col,
                       const float* __restrict__ w, int* __restrict__ cursor,
                       int2* __restrict__ packed, int E) {
    int e = blockIdx.x * 256 + threadIdx.x;
    if (e < E) {
        int pos = atomicAdd(&cursor[col[e]], 1);
        packed[pos] = make_int2(row[e], __float_as_int(w[e]));
    }
}
__global__ __launch_bounds__(256) void k_degw(const int2* __restrict__ packed,
                                              const int* __restrict__ ptr,
                                              float* __restrict__ dinv, int N) {
    int wid = (int)(((size_t)blockIdx.x * 256 + threadIdx.x) >> 6);
    int lane = threadIdx.x & 63;
    if (wid >= N) return;
    int beg = ptr[wid], end = ptr[wid + 1];
    float s = 0.0f;
    for (int k = beg + lane; k < end; k += 64) s += __int_as_float(packed[k].y);
#pragma unroll
    for (int off = 32; off; off >>= 1) s += __shfl_xor(s, off);
    if (lane == 0) {
        float d = 1.0f + s;
        dinv[wid] = d > 0.0f ? rsqrtf(d) : 0.0f;
    }
}
__global__ __launch_bounds__(256) void k_gather(
        const int2* __restrict__ packed, const int* __restrict__ ptr,
        const float* __restrict__ dinv, const float* __restrict__ nf,
        float* __restrict__ out, int N) {
    int wid = (int)(((size_t)blockIdx.x * 256 + threadIdx.x) >> 6);
    int lane = threadIdx.x & 63;
    if (wid >= N) return;
    int c = wid;
    int beg = ptr[c], end = ptr[c + 1];
    float dc = dinv[c];
    int half = lane >> 5;
    int fl = lane & 31;
    float4 acc = {0.f, 0.f, 0.f, 0.f};
    for (int k = beg; k < end; k += 2) {
        int idx = k + half;
        bool v = idx < end;
        int2 p = packed[v ? idx : beg];
        float nrm = v ? dc * __int_as_float(p.y) * dinv[p.x] : 0.0f;
        float4 x = ((const float4*)(nf + (size_t)p.x * 128))[fl];
        acc.x += nrm * x.x; acc.y += nrm * x.y;
        acc.z += nrm * x.z; acc.w += nrm * x.w;
    }
    acc.x += __shfl_xor(acc.x, 32);
    acc.y += __shfl_xor(acc.y, 32);
    acc.z += __shfl_xor(acc.z, 32);
    acc.w += __shfl_xor(acc.w, 32);
    if (half == 0) {
        float s2 = dc * dc;
        float4 sf = ((const float4*)(nf + (size_t)c * 128))[fl];
        acc.x += s2 * sf.x; acc.y += s2 * sf.y;
        acc.z += s2 * sf.z; acc.w += s2 * sf.w;
        ((float4*)(out + (size_t)c * 128))[fl] = acc;
    }
}
__global__ void k_initA(float* __restrict__ deg, float* __restrict__ sums, int N) {
    int i = blockIdx.x * 256 + threadIdx.x;
    if (i < N) deg[i] = 1.0f;
    if (blockIdx.x == 0 && threadIdx.x < 512) sums[threadIdx.x] = 0.0f;
}
__global__ void k_deg(const int* __restrict__ col, const float* __restrict__ w,
                      float* __restrict__ deg, int E) {
    int e = blockIdx.x * 256 + threadIdx.x;
    if (e < E) atomicAdd(&deg[col[e]], w[e]);
}
__global__ void k_dinv(float* __restrict__ deg, int N) {
    int i = blockIdx.x * 256 + threadIdx.x;
    if (i < N) { float d = deg[i]; deg[i] = d > 0.0f ? rsqrtf(d) : 0.0f; }
}
__global__ void k_self(const float* __restrict__ nf, const float* __restrict__ dinv,
                       float* __restrict__ agg, int N) {
    size_t i = (size_t)blockIdx.x * 256 + threadIdx.x;
    if (i >= (size_t)N * 32) return;
    int node = (int)(i >> 5);
    float s = dinv[node]; s = s * s;
    float4 v = ((const float4*)nf)[i];
    v.x *= s; v.y *= s; v.z *= s; v.w *= s;
    ((float4*)agg)[i] = v;
}
__global__ __launch_bounds__(256) void k_scatter(
        const int* __restrict__ row, const int* __restrict__ col,
        const float* __restrict__ w, const float* __restrict__ dinv,
        const float* __restrict__ nf, float* __restrict__ agg, int E) {
    int wid = (int)(((size_t)blockIdx.x * blockDim.x + threadIdx.x) >> 6);
    int lane = threadIdx.x & 63;
    if (wid >= E) return;
    int r = row[wid], c = col[wid];
    float nrm = dinv[r] * w[wid] * dinv[c];
    float2 v = ((const float2*)(nf + (size_t)r * 128))[lane];
    float* dst = agg + (size_t)c * 128 + lane * 2;
    atomicAdd(dst, v.x * nrm);
    atomicAdd(dst + 1, v.y * nrm);
}

// legacy f32 VALU GEMM (fallback paths)
__global__ __launch_bounds__(256) void k_gemm2(float* __restrict__ h,
        const float* __restrict__ W, const float* __restrict__ bias,
        float* __restrict__ sums, int N) {
    __shared__ float At[2][32][132];
    __shared__ float Wt[2][32][132];
    int tid = threadIdx.x;
    int tx = tid & 15, ty = tid >> 4;
    int r0 = blockIdx.x * 128;
#define STAGE_A(buf, k0)                                                     \
    _Pragma("unroll")                                                        \
    for (int i = 0; i < 4; ++i) {                                            \
        int idx = tid + 256 * i;                                             \
        int row = idx >> 3, c4 = idx & 7;                                    \
        int gr = r0 + row; if (gr > N - 1) gr = N - 1;                       \
        float4 v = *(const float4*)&h[(size_t)gr * 128 + (k0) + c4 * 4];     \
        At[buf][c4 * 4 + 0][row] = v.x;                                      \
        At[buf][c4 * 4 + 1][row] = v.y;                                      \
        At[buf][c4 * 4 + 2][row] = v.z;                                      \
        At[buf][c4 * 4 + 3][row] = v.w;                                      \
    }
#define STAGE_W(buf, k0)                                                     \
    _Pragma("unroll")                                                        \
    for (int i = 0; i < 4; ++i) {                                            \
        int idx = tid + 256 * i;                                             \
        int kk = idx >> 5, c4 = idx & 31;                                    \
        float4 v = *(const float4*)&W[(size_t)((k0) + kk) * 128 + c4 * 4];   \
        *(float4*)&Wt[buf][kk][c4 * 4] = v;                                  \
    }
    STAGE_A(0, 0)
    STAGE_W(0, 0)
    float acc[8][8] = {};
    for (int t = 0; t < 4; ++t) {
        __syncthreads();
        if (t < 3) {
            int nb = (t + 1) & 1;
            STAGE_A(nb, (t + 1) * 32)
            STAGE_W(nb, (t + 1) * 32)
        }
        int kb = t & 1;
#pragma unroll
        for (int k = 0; k < 32; ++k) {
            float a[8], w[8];
            *(float4*)&a[0] = *(float4*)&At[kb][k][ty * 8];
            *(float4*)&a[4] = *(float4*)&At[kb][k][ty * 8 + 4];
            *(float4*)&w[0] = *(float4*)&Wt[kb][k][tx * 8];
            *(float4*)&w[4] = *(float4*)&Wt[kb][k][tx * 8 + 4];
#pragma unroll
            for (int r = 0; r < 8; ++r)
#pragma unroll
                for (int cc = 0; cc < 8; ++cc)
                    acc[r][cc] += a[r] * w[cc];
        }
    }
    float bv[8];
    *(float4*)&bv[0] = *(const float4*)&bias[tx * 8];
    *(float4*)&bv[4] = *(const float4*)&bias[tx * 8 + 4];
    float s[8] = {}, sq[8] = {};
#pragma unroll
    for (int r = 0; r < 8; ++r) {
        int gr = r0 + ty * 8 + r;
        if (gr < N) {
            float o[8];
#pragma unroll
            for (int cc = 0; cc < 8; ++cc) {
                o[cc] = fmaxf(acc[r][cc] + bv[cc], 0.0f);
                s[cc] += o[cc];
                sq[cc] += o[cc] * o[cc];
            }
            float4* dst = (float4*)&h[(size_t)gr * 128 + tx * 8];
            dst[0] = make_float4(o[0], o[1], o[2], o[3]);
            dst[1] = make_float4(o[4], o[5], o[6], o[7]);
        }
    }
    float* ls = &At[0][0][0];
    __syncthreads();
#pragma unroll
    for (int cc = 0; cc < 8; ++cc) {
        ls[ty * 128 + tx * 8 + cc] = s[cc];
        ls[2048 + ty * 128 + tx * 8 + cc] = sq[cc];
    }
    __syncthreads();
    if (tid < 128) {
        float ssum = 0.f, sqsum = 0.f;
#pragma unroll
        for (int u = 0; u < 16; ++u) {
            ssum += ls[u * 128 + tid];
            sqsum += ls[2048 + u * 128 + tid];
        }
        atomicAdd(&sums[tid], ssum);
        atomicAdd(&sums[128 + tid], sqsum);
    }
#undef STAGE_A
#undef STAGE_W
}

extern "C" void kernel_launch(void* const* d_in, const int* in_sizes, int n_in,
                              void* d_out, int out_size, void* d_ws, size_t ws_size,
                              hipStream_t stream) {
    const float* nf    = (const float*)d_in[0];
    const int*   ei    = (const int*)d_in[1];
    const float* ew    = (const float*)d_in[2];
    const float* W     = (const float*)d_in[3];
    const float* bias  = (const float*)d_in[4];
    const float* gamma = (const float*)d_in[5];
    const float* beta  = (const float*)d_in[6];
    float* out = (float*)d_out;

    const int N = in_sizes[0] / 128;
    const int E = in_sizes[2];
    const int* row = ei;
    const int* col = ei + E;

    int nb_n  = (N + 255) / 256;
    int nb_e  = (E + 255) / 256;
    int nb_w  = (int)(((size_t)N + 3) / 4);
    int nb_v4 = (int)(((size_t)N * 32 + 255) / 256);
    int nbk   = (N + BKT_SZ - 1) >> BKT_BITS;
    int nb_c  = (E + CHUNK - 1) / CHUNK;
    int nconv = (int)(((size_t)N * 16 + 255) / 256);
    size_t n16 = (size_t)N * 16;
    size_t tt_words = (size_t)64 * N > (size_t)E ? (size_t)64 * N : (size_t)E;

    // ---- path-1 layout ----
    float* dinv = (float*)d_ws;                  // N
    int*   ptr  = (int*)d_ws + N;                // N+1
    float* sums = (float*)d_ws + 2 * N + 1;      // 512
    int*   bbase1 = (int*)d_ws + 2 * N + 513;    // nbk+1
    int*   btot   = bbase1 + nbk + 1;            // nbk
    int*   blkoff = btot + nbk;                  // nbk*nb_c
    size_t wt_off = ((size_t)(2 * N + 514 + 2 * nbk) + (size_t)nbk * nb_c + 3) & ~(size_t)3;
    unsigned* wtb = (unsigned*)((int*)d_ws + wt_off);             // 8192
    size_t pk_off = (wt_off + 8192 + 3) & ~(size_t)3;
    unsigned* p1_packed = (unsigned*)((int*)d_ws + pk_off);       // E
    size_t tt_off = (pk_off + (size_t)E + 3) & ~(size_t)3;
    unsigned* p1_tmp = (unsigned*)((int*)d_ws + tt_off);          // tmp(E)/tab(64N)
    unsigned* p1_tab = (unsigned*)((int*)d_ws + tt_off);
    size_t ab_off = (tt_off + tt_words + 3) & ~(size_t)3;
    unsigned* aggb = (unsigned*)((int*)d_ws + ab_off);            // 64N
    size_t need_p1 = (ab_off + (size_t)64 * N) * 4;

    // ---- path-2 layout (4B tmp format) ----
    float* dinv2 = (float*)d_ws;
    int*   ptr2  = (int*)d_ws + N;
    int*   cnt3  = (int*)d_ws + 2 * N + 1;
    float* sums2 = (float*)d_ws + 3 * N + 1;
    int*   bsum2 = (int*)d_ws + 3 * N + 513;
    int*   bbase2 = (int*)d_ws + 3 * N + 1025;
    int*   bcur2  = bbase2 + nbk + 1;
    size_t pk2 = ((size_t)(3 * N + 1026 + 2 * nbk) + 3) & ~(size_t)3;
    unsigned* packed2 = (unsigned*)((int*)d_ws + pk2);            // E
    size_t tt2 = (pk2 + (size_t)E + 3) & ~(size_t)3;
    unsigned* tmp2 = (unsigned*)((int*)d_ws + tt2);
    unsigned* tab2 = (unsigned*)((int*)d_ws + tt2);
    size_t need_full2 = (tt2 + tt_words) * 4;

    // ---- path-3 layout (int2 packed, f32 gather) ----
    int2*  packed3 = (int2*)((int*)d_ws + pk2);                   // 2E
    size_t need_csr3 = (pk2 + (size_t)2 * E) * 4;

    if (nbk <= MAX_BKT && ws_size >= need_p1) {
        k_bhist2<<<nb_c, 256, 0, stream>>>(col, blkoff, W, wtb, E, nbk, nb_c);
        k_bscan2a<<<(nbk + 255) / 256, 256, 0, stream>>>(blkoff, btot, nbk, nb_c);
        k_bscan2b<<<1, 1024, 0, stream>>>(btot, bbase1, ptr, sums, nbk, N, E);
        k_passA3<<<nb_c, 256, 0, stream>>>(row, col, ew, blkoff, bbase1, p1_tmp, E, nbk, nb_c);
        k_passB2<<<nbk, 256, 0, stream>>>(p1_tmp, bbase1, p1_packed, ptr, dinv, N);
        k_conv2<<<nconv, 256, 0, stream>>>(nf, dinv, (uint4*)p1_tab, N);
        k_gatherw5<<<nb_w, 256, 0, stream>>>(p1_packed, ptr, dinv, p1_tab, aggb, N);
        k_gemm4<<<(N + 127) / 128, 256, 0, stream>>>(aggb, wtb, bias, sums, N);
        k_bnapplyB2<<<(int)((n16 + 255) / 256), 256, 0, stream>>>(aggb, sums, gamma, beta, out, n16, N);
        return;
    }

    if (nbk <= MAX_BKT && ws_size >= need_full2) {
        k_init0<<<(max(nbk, 512) + 255) / 256, 256, 0, stream>>>(bcur2, sums2, nbk);
        k_bhist<<<nb_c, 256, 0, stream>>>(col, bcur2, E, nbk);
        k_bscan<<<1, 1024, 0, stream>>>(bcur2, bbase2, bcur2, ptr2, nbk, N, E);
        k_passA2<<<nb_c, 256, 0, stream>>>(row, col, ew, bcur2, tmp2, E, nbk);
        k_passB2<<<nbk, 256, 0, stream>>>(tmp2, bbase2, packed2, ptr2, dinv2, N);
        k_conv2<<<nconv, 256, 0, stream>>>(nf, dinv2, (uint4*)tab2, N);
        k_gatherwF<<<nb_w, 256, 0, stream>>>(packed2, ptr2, dinv2, tab2, out, N);
        k_gemm2<<<(N + 127) / 128, 256, 0, stream>>>(out, W, bias, sums2, N);
        k_bnfin<<<1, 128, 0, stream>>>(sums2, gamma, beta, N);
        k_bnapply<<<nb_v4, 256, 0, stream>>>(out, sums2, (size_t)N * 32);
        return;
    }

    if (ws_size >= need_csr3) {
        k_init<<<nb_n, 256, 0, stream>>>(cnt3, sums2, N);
        k_count<<<nb_e, 256, 0, stream>>>(col, cnt3, E);
        kS1<<<nb_n, 256, 0, stream>>>(cnt3, ptr2, bsum2, N);
        kS2<<<1, 512, 0, stream>>>(bsum2, ptr2, nb_n, N);
        kS3<<<nb_n, 256, 0, stream>>>(ptr2, cnt3, bsum2, N);
        k_fill<<<nb_e, 256, 0, stream>>>(row, col, ew, cnt3, packed3, E);
        k_degw<<<nb_w, 256, 0, stream>>>(packed3, ptr2, dinv2, N);
        k_gather<<<nb_w, 256, 0, stream>>>(packed3, ptr2, dinv2, nf, out, N);
        k_gemm2<<<(N + 127) / 128, 256, 0, stream>>>(out, W, bias, sums2, N);
        k_bnfin<<<1, 128, 0, stream>>>(sums2, gamma, beta, N);
        k_bnapply<<<nb_v4, 256, 0, stream>>>(out, sums2, (size_t)N * 32);
        return;
    }

    {
        float* deg = (float*)d_ws;
        float* sm  = (float*)d_ws + N;
        k_initA<<<nb_n, 256, 0, stream>>>(deg, sm, N);
        k_deg<<<nb_e, 256, 0, stream>>>(col, ew, deg, E);
        k_dinv<<<nb_n, 256, 0, stream>>>(deg, N);
        k_self<<<nb_v4, 256, 0, stream>>>(nf, deg, out, N);
        k_scatter<<<(E + 3) / 4, 256, 0, stream>>>(row, col, ew, deg, nf, out, E);
        k_gemm2<<<(N + 127) / 128, 256, 0, stream>>>(out, W, bias, sm, N);
        k_bnfin<<<1, 128, 0, stream>>>(sm, gamma, beta, N);
        k_bnapply<<<nb_v4, 256, 0, stream>>>(out, sm, (size_t)N * 32);
    }
}

// Round 13
// 323.996 us; speedup vs baseline: 2.6294x; 1.0467x over previous
//
#include <hip/hip_runtime.h>
#include <hip/hip_bf16.h>

// GCN layer: h = BN(ReLU(segment_sum(norm * (nf@W))[col] + b))
// R1: CSR gather.  R2: bf16 table.  R4: block-reservation radix partition.
// R5: fold dinv into tab.  R6: MFMA bf16 GEMM, bf16 h.
// R8: zero-waste wave-per-node gather (107us, at ~3.7TB/s random-256B
//     fabric ceiling; R7/R9 restructures regressed).
// R11: split scan restored.  R12: gemm4 (no W LDS) regressed +21us.
// R13: revert gemm to gemm3b (W staged in LDS); fuse conv2 into passB
//      (k_passB3: bucket block converts its own 128 nf rows to tab using
//      in-LDS dinv) -- one fewer full pass; keep fused bnapplyB2.

#define BKT_BITS 7
#define BKT_SZ 128
#define MAX_BKT 1024        // N <= 131072 (row fits 17 bits)
#define CHUNK 8192

typedef __attribute__((ext_vector_type(8))) short bf16x8;
typedef __attribute__((ext_vector_type(4))) float f32x4;

__device__ __forceinline__ unsigned bf16rn(float f) {
    unsigned x = __float_as_uint(f);
    return (x + 0x7fffu + ((x >> 16) & 1u)) >> 16;
}
__device__ __forceinline__ float bflo(unsigned u) { return __uint_as_float(u << 16); }
__device__ __forceinline__ float bfhi(unsigned u) { return __uint_as_float(u & 0xffff0000u); }

// ---------------- path 1: single-histogram radix partition ----------------
// + convW folded into block 0
__global__ __launch_bounds__(256) void k_bhist2(const int* __restrict__ col,
        int* __restrict__ blkoff, const float* __restrict__ Wm,
        unsigned* __restrict__ WT, int E, int nb, int nbc) {
    __shared__ int h[MAX_BKT];
    for (int i = threadIdx.x; i < nb; i += 256) h[i] = 0;
    __syncthreads();
    int base = blockIdx.x * CHUNK, lim = min(base + CHUNK, E);
    for (int e = base + threadIdx.x; e < lim; e += 256)
        atomicAdd(&h[col[e] >> BKT_BITS], 1);
    __syncthreads();
    for (int i = threadIdx.x; i < nb; i += 256)
        blkoff[(size_t)i * nbc + blockIdx.x] = h[i];
    if (blockIdx.x == 0) {
        // WT[j][k2] = bf16(W[2k2][j]) | bf16(W[2k2+1][j])<<16
        for (int i = threadIdx.x; i < 128 * 64; i += 256) {
            int j = i >> 6, w = i & 63;
            float a = Wm[(size_t)(2 * w) * 128 + j];
            float b = Wm[(size_t)(2 * w + 1) * 128 + j];
            WT[i] = bf16rn(a) | (bf16rn(b) << 16);
        }
    }
}

// per-bucket exclusive scan over blocks (one thread per bucket, multi-block)
__global__ void k_bscan2a(int* __restrict__ blkoff, int* __restrict__ btot,
                          int nb, int nbc) {
    int b = blockIdx.x * 256 + threadIdx.x;
    if (b >= nb) return;
    int* p = blkoff + (size_t)b * nbc;
    int run = 0;
#pragma unroll 4
    for (int i = 0; i < nbc; ++i) { int c = p[i]; p[i] = run; run += c; }
    btot[b] = run;
}

// scan bucket totals -> bbase; also ptr[N]=E and zero BN sums
__global__ __launch_bounds__(1024) void k_bscan2b(const int* __restrict__ btot,
        int* __restrict__ bbase, int* __restrict__ ptr, float* __restrict__ sums,
        int nb, int N, int E) {
    __shared__ int ls[1024];
    int t = threadIdx.x;
    int v = (t < nb) ? btot[t] : 0;
    ls[t] = v;
    __syncthreads();
    for (int off = 1; off < 1024; off <<= 1) {
        int u = (t >= off) ? ls[t - off] : 0;
        __syncthreads();
        ls[t] += u;
        __syncthreads();
    }
    if (t < nb) bbase[t] = ls[t] - v;
    if (t == nb - 1) bbase[nb] = ls[t];
    if (t == 0) ptr[N] = E;
    if (t < 512) sums[t] = 0.0f;
}

// scatter into bucket-grouped tmp: rec = row17<<15 | col7<<8 | w8
__global__ __launch_bounds__(256) void k_passA3(
        const int* __restrict__ row, const int* __restrict__ col,
        const float* __restrict__ w, const int* __restrict__ blkoff,
        const int* __restrict__ bbase, unsigned* __restrict__ tmp,
        int E, int nb, int nbc) {
    __shared__ int cur[MAX_BKT];
    for (int i = threadIdx.x; i < nb; i += 256)
        cur[i] = bbase[i] + blkoff[(size_t)i * nbc + blockIdx.x];
    __syncthreads();
    int base = blockIdx.x * CHUNK, lim = min(base + CHUNK, E);
    for (int e = base + threadIdx.x; e < lim; e += 256) {
        int c = col[e];
        int q8 = (int)(w[e] * 256.0f + 0.5f);
        if (q8 > 255) q8 = 255;
        unsigned rec = ((unsigned)row[e] << 15) | ((unsigned)(c & 127) << 8) | (unsigned)q8;
        int pos = atomicAdd(&cur[c >> BKT_BITS], 1);
        tmp[pos] = rec;
    }
}

// pass B (fused tab conv): per-node offsets in LDS, place edges as
// row17|wbf15 (wbf15 = bf16 bits of w*dinv[col]), fused degree -> dinv,
// AND convert this bucket's 128 nf rows to bf16 tab (dinv folded).
__global__ __launch_bounds__(256) void k_passB3(
        const unsigned* __restrict__ tmp, const int* __restrict__ bbase,
        const float* __restrict__ nf, unsigned* __restrict__ tab,
        unsigned* __restrict__ packed, int* __restrict__ ptr,
        float* __restrict__ dinv, int N) {
    __shared__ int hcnt[BKT_SZ];
    __shared__ int wsumi[BKT_SZ];
    __shared__ int cur[BKT_SZ];
    __shared__ float dcl[BKT_SZ];
    int b = blockIdx.x;
    int t = threadIdx.x;
    int node0 = b << BKT_BITS;
    if (t < BKT_SZ) { hcnt[t] = 0; wsumi[t] = 0; }
    __syncthreads();
    int beg = bbase[b], end = bbase[b + 1];
    for (int k = beg + t; k < end; k += 256) {
        unsigned p = tmp[k];
        int li = (p >> 8) & 127;
        atomicAdd(&hcnt[li], 1);
        atomicAdd(&wsumi[li], (int)(p & 255u));
    }
    __syncthreads();
    if (t < BKT_SZ) cur[t] = hcnt[t];
    __syncthreads();
    for (int off = 1; off < BKT_SZ; off <<= 1) {
        int v = (t < BKT_SZ && t >= off) ? cur[t - off] : 0;
        __syncthreads();
        if (t < BKT_SZ) cur[t] += v;
        __syncthreads();
    }
    if (t < BKT_SZ) {
        int p = beg + cur[t] - hcnt[t];
        cur[t] = p;
        float d = 1.0f + (float)wsumi[t] * (1.0f / 256.0f);
        float dc = rsqrtf(d);
        dcl[t] = dc;
        int n = node0 + t;
        if (n < N) { ptr[n] = p; dinv[n] = dc; }
    }
    __syncthreads();
    // place edges at final CSR positions
    for (int k = beg + t; k < end; k += 256) {
        unsigned p = tmp[k];
        int li = (p >> 8) & 127;
        int pos = atomicAdd(&cur[li], 1);
        float fw = (float)(p & 255u) * (1.0f / 256.0f) * dcl[li];
        unsigned wb = bf16rn(fw) & 0x7FFFu;
        packed[pos] = ((p >> 15) << 15) | wb;
    }
    // convert this bucket's nf rows to tab (coalesced, dinv from LDS)
    for (int i = t; i < BKT_SZ * 16; i += 256) {
        int r = i >> 4, q4 = i & 15;
        int n = node0 + r;
        if (n < N) {
            float dv = dcl[r];
            const float4* src = (const float4*)(nf + (size_t)n * 128 + q4 * 8);
            float4 a = src[0], bb = src[1];
            uint4 rr;
            rr.x = bf16rn(a.x * dv) | (bf16rn(a.y * dv) << 16);
            rr.y = bf16rn(a.z * dv) | (bf16rn(a.w * dv) << 16);
            rr.z = bf16rn(bb.x * dv) | (bf16rn(bb.y * dv) << 16);
            rr.w = bf16rn(bb.z * dv) | (bf16rn(bb.w * dv) << 16);
            *(uint4*)(tab + (size_t)n * 64 + q4 * 4) = rr;
        }
    }
}

// pass B (no tab fusion) for path 2
__global__ __launch_bounds__(256) void k_passB2(
        const unsigned* __restrict__ tmp, const int* __restrict__ bbase,
        unsigned* __restrict__ packed, int* __restrict__ ptr,
        float* __restrict__ dinv, int N) {
    __shared__ int hcnt[BKT_SZ];
    __shared__ int wsumi[BKT_SZ];
    __shared__ int cur[BKT_SZ];
    __shared__ float dcl[BKT_SZ];
    int b = blockIdx.x;
    int t = threadIdx.x;
    if (t < BKT_SZ) { hcnt[t] = 0; wsumi[t] = 0; }
    __syncthreads();
    int beg = bbase[b], end = bbase[b + 1];
    for (int k = beg + t; k < end; k += 256) {
        unsigned p = tmp[k];
        int li = (p >> 8) & 127;
        atomicAdd(&hcnt[li], 1);
        atomicAdd(&wsumi[li], (int)(p & 255u));
    }
    __syncthreads();
    if (t < BKT_SZ) cur[t] = hcnt[t];
    __syncthreads();
    for (int off = 1; off < BKT_SZ; off <<= 1) {
        int v = (t < BKT_SZ && t >= off) ? cur[t - off] : 0;
        __syncthreads();
        if (t < BKT_SZ) cur[t] += v;
        __syncthreads();
    }
    if (t < BKT_SZ) {
        int p = beg + cur[t] - hcnt[t];
        cur[t] = p;
        float d = 1.0f + (float)wsumi[t] * (1.0f / 256.0f);
        float dc = rsqrtf(d);
        dcl[t] = dc;
        int n = (b << BKT_BITS) + t;
        if (n < N) { ptr[n] = p; dinv[n] = dc; }
    }
    __syncthreads();
    for (int k = beg + t; k < end; k += 256) {
        unsigned p = tmp[k];
        int li = (p >> 8) & 127;
        int pos = atomicAdd(&cur[li], 1);
        float fw = (float)(p & 255u) * (1.0f / 256.0f) * dcl[li];
        unsigned wb = bf16rn(fw) & 0x7FFFu;
        packed[pos] = ((p >> 15) << 15) | wb;
    }
}

// tab[r] = bf16(nf[r] * dinv[r])  (paths 2/3)
__global__ void k_conv2(const float* __restrict__ nf, const float* __restrict__ dinv,
                        uint4* __restrict__ tab, int N) {
    size_t i = (size_t)blockIdx.x * 256 + threadIdx.x;
    if (i >= (size_t)N * 16) return;
    int n = (int)(i >> 4);
    float dv = dinv[n];
    const float4* src = (const float4*)nf + 2 * i;
    float4 a = src[0], b = src[1];
    uint4 r;
    r.x = bf16rn(a.x * dv) | (bf16rn(a.y * dv) << 16);
    r.y = bf16rn(a.z * dv) | (bf16rn(a.w * dv) << 16);
    r.z = bf16rn(b.x * dv) | (bf16rn(b.y * dv) << 16);
    r.w = bf16rn(b.z * dv) | (bf16rn(b.w * dv) << 16);
    tab[i] = r;
}

#define EDGE_FMA(aX, nX, tX)                                     \
    aX[0] += nX * bflo(tX.x); aX[1] += nX * bfhi(tX.x);          \
    aX[2] += nX * bflo(tX.y); aX[3] += nX * bfhi(tX.y);          \
    aX[4] += nX * bflo(tX.z); aX[5] += nX * bfhi(tX.z);          \
    aX[6] += nX * bflo(tX.w); aX[7] += nX * bfhi(tX.w);

// gather (R8 structure): wave per node; uncond 4-deep main, 2-deep mid,
// exec-masked tail. rec = row17|wbf15; dinv[row] folded in tab.
__global__ __launch_bounds__(256) void k_gatherw5(
        const unsigned* __restrict__ packed, const int* __restrict__ ptr,
        const float* __restrict__ dinv, const unsigned* __restrict__ tab,
        unsigned* __restrict__ aggb, int N) {
    int wid = (int)(((size_t)blockIdx.x * 256 + threadIdx.x) >> 6);
    int lane = threadIdx.x & 63;
    if (wid >= N) return;
    int beg = ptr[wid], end = ptr[wid + 1];
    float dc = dinv[wid];
    int q = lane >> 4;       // edge slot
    int fl = lane & 15;      // features [8*fl, 8*fl+8)
    float a0[8] = {}, a1[8] = {}, a2[8] = {}, a3[8] = {};
    int k = beg;
    for (; k + 16 <= end; k += 16) {
        unsigned p0 = packed[k + q];
        unsigned p1 = packed[k + 4 + q];
        unsigned p2 = packed[k + 8 + q];
        unsigned p3 = packed[k + 12 + q];
        uint4 t0 = *(const uint4*)(tab + (size_t)(p0 >> 15) * 64 + fl * 4);
        uint4 t1 = *(const uint4*)(tab + (size_t)(p1 >> 15) * 64 + fl * 4);
        uint4 t2 = *(const uint4*)(tab + (size_t)(p2 >> 15) * 64 + fl * 4);
        uint4 t3 = *(const uint4*)(tab + (size_t)(p3 >> 15) * 64 + fl * 4);
        float n0 = bflo(p0 & 0x7FFFu);
        float n1 = bflo(p1 & 0x7FFFu);
        float n2 = bflo(p2 & 0x7FFFu);
        float n3 = bflo(p3 & 0x7FFFu);
        EDGE_FMA(a0, n0, t0)
        EDGE_FMA(a1, n1, t1)
        EDGE_FMA(a2, n2, t2)
        EDGE_FMA(a3, n3, t3)
    }
    if (k + 8 <= end) {
        unsigned p0 = packed[k + q];
        unsigned p1 = packed[k + 4 + q];
        uint4 t0 = *(const uint4*)(tab + (size_t)(p0 >> 15) * 64 + fl * 4);
        uint4 t1 = *(const uint4*)(tab + (size_t)(p1 >> 15) * 64 + fl * 4);
        float n0 = bflo(p0 & 0x7FFFu);
        float n1 = bflo(p1 & 0x7FFFu);
        EDGE_FMA(a0, n0, t0)
        EDGE_FMA(a1, n1, t1)
        k += 8;
    }
    for (; k < end; k += 4) {
        int i0 = k + q;
        if (i0 < end) {      // exec-masked: no loads from invalid lanes
            unsigned p0 = packed[i0];
            uint4 t0 = *(const uint4*)(tab + (size_t)(p0 >> 15) * 64 + fl * 4);
            float n0 = bflo(p0 & 0x7FFFu);
            EDGE_FMA(a0, n0, t0)
        }
    }
#pragma unroll
    for (int j = 0; j < 8; ++j) {
        float s = (a0[j] + a1[j]) + (a2[j] + a3[j]);
        s += __shfl_xor(s, 16);
        s += __shfl_xor(s, 32);
        a0[j] = s;
    }
    if (q == 0) {
        uint4 t = *(const uint4*)(tab + (size_t)wid * 64 + fl * 4);
        EDGE_FMA(a0, dc, t)   // self: dc*tab[c]
        uint4 r;
        r.x = bf16rn(a0[0]) | (bf16rn(a0[1]) << 16);
        r.y = bf16rn(a0[2]) | (bf16rn(a0[3]) << 16);
        r.z = bf16rn(a0[4]) | (bf16rn(a0[5]) << 16);
        r.w = bf16rn(a0[6]) | (bf16rn(a0[7]) << 16);
        *(uint4*)(aggb + (size_t)wid * 64 + fl * 4) = r;
    }
}

// gather -> f32 rows into out (path-2 fallback; same packed format)
__global__ __launch_bounds__(256) void k_gatherwF(
        const unsigned* __restrict__ packed, const int* __restrict__ ptr,
        const float* __restrict__ dinv, const unsigned* __restrict__ tab,
        float* __restrict__ out, int N) {
    int wid = (int)(((size_t)blockIdx.x * 256 + threadIdx.x) >> 6);
    int lane = threadIdx.x & 63;
    if (wid >= N) return;
    int beg = ptr[wid], end = ptr[wid + 1];
    float dc = dinv[wid];
    int q = lane >> 4;
    int fl = lane & 15;
    float a0[8] = {}, a1[8] = {};
    int k = beg;
    for (; k + 8 <= end; k += 8) {
        unsigned p0 = packed[k + q];
        unsigned p1 = packed[k + 4 + q];
        uint4 t0 = *(const uint4*)(tab + (size_t)(p0 >> 15) * 64 + fl * 4);
        uint4 t1 = *(const uint4*)(tab + (size_t)(p1 >> 15) * 64 + fl * 4);
        float n0 = bflo(p0 & 0x7FFFu);
        float n1 = bflo(p1 & 0x7FFFu);
        EDGE_FMA(a0, n0, t0)
        EDGE_FMA(a1, n1, t1)
    }
    for (; k < end; k += 4) {
        int i0 = k + q;
        if (i0 < end) {
            unsigned p0 = packed[i0];
            uint4 t0 = *(const uint4*)(tab + (size_t)(p0 >> 15) * 64 + fl * 4);
            float n0 = bflo(p0 & 0x7FFFu);
            EDGE_FMA(a0, n0, t0)
        }
    }
#pragma unroll
    for (int j = 0; j < 8; ++j) {
        float s = a0[j] + a1[j];
        s += __shfl_xor(s, 16);
        s += __shfl_xor(s, 32);
        a0[j] = s;
    }
    if (q == 0) {
        uint4 t = *(const uint4*)(tab + (size_t)wid * 64 + fl * 4);
        EDGE_FMA(a0, dc, t)
        float4* dst = (float4*)(out + (size_t)wid * 128 + fl * 8);
        dst[0] = make_float4(a0[0], a0[1], a0[2], a0[3]);
        dst[1] = make_float4(a0[4], a0[5], a0[6], a0[7]);
    }
}

// MFMA bf16 GEMM (W staged in LDS -- proven config): aggb (bf16) ->
// h = relu(aggb@W+b) -> aggb (bf16, in place); fused BN partial sums.
__global__ __launch_bounds__(256) void k_gemm3b(
        unsigned* aggb, const unsigned* __restrict__ WT,
        const float* __restrict__ bias, float* __restrict__ sums, int N) {
    __shared__ unsigned A_l[128][68];
    __shared__ unsigned W_l[128][68];
    __shared__ float bs[256];
    int tid = threadIdx.x;
    int r0 = blockIdx.x * 128;
    bs[tid] = 0.0f;
    {
        int j = tid >> 1, h = tid & 1;
        const uint4* src = (const uint4*)(WT + j * 64 + h * 32);
#pragma unroll
        for (int i = 0; i < 8; ++i)
            *(uint4*)&W_l[j][h * 32 + i * 4] = src[i];
    }
    {
        int j = tid >> 1, h = tid & 1;
        int gr = r0 + j;
        if (gr < N) {
            const uint4* src = (const uint4*)(aggb + (size_t)gr * 64 + h * 32);
#pragma unroll
            for (int i = 0; i < 8; ++i)
                *(uint4*)&A_l[j][h * 32 + i * 4] = src[i];
        } else {
            uint4 z = {0, 0, 0, 0};
#pragma unroll
            for (int i = 0; i < 8; ++i)
                *(uint4*)&A_l[j][h * 32 + i * 4] = z;
        }
    }
    __syncthreads();

    int wv = tid >> 6, l = tid & 63;
    int lr = l & 15, lk = l >> 4;
    f32x4 acc[2][8] = {};
#pragma unroll
    for (int ks = 0; ks < 4; ++ks) {
        bf16x8 a0 = *(bf16x8*)&A_l[wv * 32 + lr][ks * 16 + lk * 4];
        bf16x8 a1 = *(bf16x8*)&A_l[wv * 32 + 16 + lr][ks * 16 + lk * 4];
#pragma unroll
        for (int nt = 0; nt < 8; ++nt) {
            bf16x8 b = *(bf16x8*)&W_l[nt * 16 + lr][ks * 16 + lk * 4];
            acc[0][nt] = __builtin_amdgcn_mfma_f32_16x16x32_bf16(a0, b, acc[0][nt], 0, 0, 0);
            acc[1][nt] = __builtin_amdgcn_mfma_f32_16x16x32_bf16(a1, b, acc[1][nt], 0, 0, 0);
        }
    }

    unsigned short* ab = (unsigned short*)aggb;
#pragma unroll
    for (int nt = 0; nt < 8; ++nt) {
        int colc = nt * 16 + lr;
        float bc = bias[colc];
        float s = 0.0f, sq = 0.0f;
#pragma unroll
        for (int ms = 0; ms < 2; ++ms) {
#pragma unroll
            for (int p = 0; p < 4; ++p) {
                int rrow = r0 + wv * 32 + ms * 16 + lk * 4 + p;
                float v = fmaxf(acc[ms][nt][p] + bc, 0.0f);
                if (rrow < N) {
                    ab[(size_t)rrow * 128 + colc] = (unsigned short)bf16rn(v);
                    s += v;
                    sq += v * v;
                }
            }
        }
        s += __shfl_xor(s, 16);  s += __shfl_xor(s, 32);
        sq += __shfl_xor(sq, 16); sq += __shfl_xor(sq, 32);
        if (l < 16) {
            atomicAdd(&bs[colc], s);
            atomicAdd(&bs[128 + colc], sq);
        }
    }
    __syncthreads();
    if (tid < 128) {
        atomicAdd(&sums[tid], bs[tid]);
        atomicAdd(&sums[128 + tid], bs[128 + tid]);
    }
}

// BN finalize+apply fused: bf16 aggb -> f32 out
__global__ __launch_bounds__(256) void k_bnapplyB2(
        const unsigned* __restrict__ aggb, const float* __restrict__ sums,
        const float* __restrict__ gamma, const float* __restrict__ beta,
        float* __restrict__ out, size_t n16, int N) {
    __shared__ float sc[128], sh[128];
    int t = threadIdx.x;
    if (t < 128) {
        float inv_n = 1.0f / (float)N;
        float mean = sums[t] * inv_n;
        float var = sums[128 + t] * inv_n - mean * mean;
        float s = rsqrtf(var + 1e-5f) * gamma[t];
        sc[t] = s;
        sh[t] = beta[t] - mean * s;
    }
    __syncthreads();
    size_t i = (size_t)blockIdx.x * 256 + threadIdx.x;
    if (i >= n16) return;
    int g = (int)(i & 15);
    uint4 v = ((const uint4*)aggb)[i];
    float4 sc0 = *(float4*)&sc[g * 8];
    float4 sc1 = *(float4*)&sc[g * 8 + 4];
    float4 sh0 = *(float4*)&sh[g * 8];
    float4 sh1 = *(float4*)&sh[g * 8 + 4];
    float4 o0, o1;
    o0.x = bflo(v.x) * sc0.x + sh0.x;
    o0.y = bfhi(v.x) * sc0.y + sh0.y;
    o0.z = bflo(v.y) * sc0.z + sh0.z;
    o0.w = bfhi(v.y) * sc0.w + sh0.w;
    o1.x = bflo(v.z) * sc1.x + sh1.x;
    o1.y = bfhi(v.z) * sc1.y + sh1.y;
    o1.z = bflo(v.w) * sc1.z + sh1.z;
    o1.w = bfhi(v.w) * sc1.w + sh1.w;
    ((float4*)out)[2 * i] = o0;
    ((float4*)out)[2 * i + 1] = o1;
}

__global__ void k_bnfin(float* __restrict__ sums, const float* __restrict__ gamma,
                        const float* __restrict__ beta, int N) {
    int j = threadIdx.x;
    float inv_n = 1.0f / (float)N;
    float mean = sums[j] * inv_n;
    float var = sums[128 + j] * inv_n - mean * mean;
    float sc = rsqrtf(var + 1e-5f) * gamma[j];
    sums[256 + j] = sc;
    sums[384 + j] = beta[j] - mean * sc;
}

__global__ void k_bnapply(float* __restrict__ h, const float* __restrict__ sums, size_t n4) {
    size_t i = (size_t)blockIdx.x * 256 + threadIdx.x;
    if (i >= n4) return;
    int j4 = (int)(i & 31);
    float4 v = ((float4*)h)[i];
    float4 sc = ((const float4*)(sums + 256))[j4];
    float4 sh = ((const float4*)(sums + 384))[j4];
    v.x = v.x * sc.x + sh.x;
    v.y = v.y * sc.y + sh.y;
    v.z = v.z * sc.z + sh.z;
    v.w = v.w * sc.w + sh.w;
    ((float4*)h)[i] = v;
}

// ---------------- path 2 (reservation partition, 4B tmp format) ----------
__global__ void k_init0(int* __restrict__ bcnt, float* __restrict__ sums, int nb) {
    int i = blockIdx.x * 256 + threadIdx.x;
    if (i < nb) bcnt[i] = 0;
    if (blockIdx.x == 0 && threadIdx.x < 512) sums[threadIdx.x] = 0.0f;
}
__global__ __launch_bounds__(256) void k_bhist(const int* __restrict__ col,
                                               int* __restrict__ bcnt, int E, int nb) {
    __shared__ int h[MAX_BKT];
    for (int i = threadIdx.x; i < nb; i += 256) h[i] = 0;
    __syncthreads();
    int base = blockIdx.x * CHUNK, lim = min(base + CHUNK, E);
    for (int e = base + threadIdx.x; e < lim; e += 256)
        atomicAdd(&h[col[e] >> BKT_BITS], 1);
    __syncthreads();
    for (int i = threadIdx.x; i < nb; i += 256) {
        int c = h[i];
        if (c) atomicAdd(&bcnt[i], c);
    }
}
__global__ __launch_bounds__(1024) void k_bscan(const int* __restrict__ bcnt,
        int* __restrict__ bbase, int* __restrict__ bcur,
        int* __restrict__ ptr, int nb, int N, int E) {
    __shared__ int ls[1024];
    int t = threadIdx.x;
    int v = (t < nb) ? bcnt[t] : 0;
    ls[t] = v;
    __syncthreads();
    for (int off = 1; off < 1024; off <<= 1) {
        int u = (t >= off) ? ls[t - off] : 0;
        __syncthreads();
        ls[t] += u;
        __syncthreads();
    }
    if (t < nb) {
        int ex = ls[t] - v;
        bbase[t] = ex;
        bcur[t] = ex;
    }
    if (t == nb - 1) bbase[nb] = ls[t];
    if (t == 0) ptr[N] = E;
}
__global__ __launch_bounds__(256) void k_passA2(
        const int* __restrict__ row, const int* __restrict__ col,
        const float* __restrict__ w, int* __restrict__ bcur,
        unsigned* __restrict__ tmp, int E, int nb) {
    __shared__ int h[MAX_BKT];
    for (int i = threadIdx.x; i < nb; i += 256) h[i] = 0;
    __syncthreads();
    int base = blockIdx.x * CHUNK, lim = min(base + CHUNK, E);
    for (int e = base + threadIdx.x; e < lim; e += 256)
        atomicAdd(&h[col[e] >> BKT_BITS], 1);
    __syncthreads();
    for (int i = threadIdx.x; i < nb; i += 256) {
        int c = h[i];
        if (c) h[i] = atomicAdd(&bcur[i], c);
    }
    __syncthreads();
    for (int e = base + threadIdx.x; e < lim; e += 256) {
        int c = col[e];
        int q8 = (int)(w[e] * 256.0f + 0.5f);
        if (q8 > 255) q8 = 255;
        unsigned rec = ((unsigned)row[e] << 15) | ((unsigned)(c & 127) << 8) | (unsigned)q8;
        int pos = atomicAdd(&h[c >> BKT_BITS], 1);
        tmp[pos] = rec;
    }
}

// ---------------- path 3/4 fallbacks (full precision, independent) --------
__global__ void k_init(int* __restrict__ cnt, float* __restrict__ sums, int N) {
    int i = blockIdx.x * 256 + threadIdx.x;
    if (i < N) cnt[i] = 0;
    if (blockIdx.x == 0 && threadIdx.x < 512) sums[threadIdx.x] = 0.0f;
}
__global__ void k_count(const int* __restrict__ col, int* __restrict__ cnt, int E) {
    int e = blockIdx.x * 256 + threadIdx.x;
    if (e < E) atomicAdd(&cnt[col[e]], 1);
}
__global__ __launch_bounds__(256) void kS1(const int* __restrict__ cnt,
                                           int* __restrict__ ptr,
                                           int* __restrict__ bsum, int N) {
    __shared__ int ls[256];
    int t = threadIdx.x, i = blockIdx.x * 256 + t;
    int v = (i < N) ? cnt[i] : 0;
    ls[t] = v;
    __syncthreads();
    for (int off = 1; off < 256; off <<= 1) {
        int u = (t >= off) ? ls[t - off] : 0;
        __syncthreads();
        ls[t] += u;
        __syncthreads();
    }
    if (i < N) ptr[i] = ls[t] - v;
    if (t == 255) bsum[blockIdx.x] = ls[255];
}
__global__ __launch_bounds__(512) void kS2(int* __restrict__ bsum,
                                           int* __restrict__ ptr, int NB, int N) {
    __shared__ int ls[512];
    int t = threadIdx.x;
    int chunk = (NB + 511) / 512;
    int b = t * chunk, e = min(b + chunk, NB);
    int s = 0;
    for (int i = b; i < e; ++i) s += bsum[i];
    ls[t] = s;
    __syncthreads();
    for (int off = 1; off < 512; off <<= 1) {
        int u = (t >= off) ? ls[t - off] : 0;
        __syncthreads();
        ls[t] += u;
        __syncthreads();
    }
    int run = ls[t] - s;
    for (int i = b; i < e; ++i) { int c = bsum[i]; bsum[i] = run; run += c; }
    if (t == 511) ptr[N] = ls[511];
}
__global__ void kS3(int* __restrict__ ptr, int* __restrict__ cnt,
                    const int* __restrict__ bsum, int N) {
    int i = blockIdx.x * 256 + threadIdx.x;
    if (i >= N) return;
    int p = ptr[i] + bsum[blockIdx.x];
    ptr[i] = p;
    cnt[i] = p;
}
__global__ void k_fill(const int* __restrict__ row, const int* __restrict__ col,
                       const float* __restrict__ w, int* __restrict__ cursor,
                       int2* __restrict__ packed, int E) {
    int e = blockIdx.x * 256 + threadIdx.x;
    if (e < E) {
        int pos = atomicAdd(&cursor[col[e]], 1);
        packed[pos] = make_int2(row[e], __float_as_int(w[e]));
    }
}
__global__ __launch_bounds__(256) void k_degw(const int2* __restrict__ packed,
                                              const int* __restrict__ ptr,
                                              float* __restrict__ dinv, int N) {
    int wid = (int)(((size_t)blockIdx.x * 256 + threadIdx.x) >> 6);
    int lane = threadIdx.x & 63;
    if (wid >= N) return;
    int beg = ptr[wid], end = ptr[wid + 1];
    float s = 0.0f;
    for (int k = beg + lane; k < end; k += 64) s += __int_as_float(packed[k].y);
#pragma unroll
    for (int off = 32; off; off >>= 1) s += __shfl_xor(s, off);
    if (lane == 0) {
        float d = 1.0f + s;
        dinv[wid] = d > 0.0f ? rsqrtf(d) : 0.0f;
    }
}
__global__ __launch_bounds__(256) void k_gather(
        const int2* __restrict__ packed, const int* __restrict__ ptr,
        const float* __restrict__ dinv, const float* __restrict__ nf,
        float* __restrict__ out, int N) {
    int wid = (int)(((size_t)blockIdx.x * 256 + threadIdx.x) >> 6);
    int lane = threadIdx.x & 63;
    if (wid >= N) return;
    int c = wid;
    int beg = ptr[c], end = ptr[c + 1];
    float dc = dinv[c];
    int half = lane >> 5;
    int fl = lane & 31;
    float4 acc = {0.f, 0.f, 0.f, 0.f};
    for (int k = beg; k < end; k += 2) {
        int idx = k + half;
        bool v = idx < end;
        int2 p = packed[v ? idx : beg];
        float nrm = v ? dc * __int_as_float(p.y) * dinv[p.x] : 0.0f;
        float4 x = ((const float4*)(nf + (size_t)p.x * 128))[fl];
        acc.x += nrm * x.x; acc.y += nrm * x.y;
        acc.z += nrm * x.z; acc.w += nrm * x.w;
    }
    acc.x += __shfl_xor(acc.x, 32);
    acc.y += __shfl_xor(acc.y, 32);
    acc.z += __shfl_xor(acc.z, 32);
    acc.w += __shfl_xor(acc.w, 32);
    if (half == 0) {
        float s2 = dc * dc;
        float4 sf = ((const float4*)(nf + (size_t)c * 128))[fl];
        acc.x += s2 * sf.x; acc.y += s2 * sf.y;
        acc.z += s2 * sf.z; acc.w += s2 * sf.w;
        ((float4*)(out + (size_t)c * 128))[fl] = acc;
    }
}
__global__ void k_initA(float* __restrict__ deg, float* __restrict__ sums, int N) {
    int i = blockIdx.x * 256 + threadIdx.x;
    if (i < N) deg[i] = 1.0f;
    if (blockIdx.x == 0 && threadIdx.x < 512) sums[threadIdx.x] = 0.0f;
}
__global__ void k_deg(const int* __restrict__ col, const float* __restrict__ w,
                      float* __restrict__ deg, int E) {
    int e = blockIdx.x * 256 + threadIdx.x;
    if (e < E) atomicAdd(&deg[col[e]], w[e]);
}
__global__ void k_dinv(float* __restrict__ deg, int N) {
    int i = blockIdx.x * 256 + threadIdx.x;
    if (i < N) { float d = deg[i]; deg[i] = d > 0.0f ? rsqrtf(d) : 0.0f; }
}
__global__ void k_self(const float* __restrict__ nf, const float* __restrict__ dinv,
                       float* __restrict__ agg, int N) {
    size_t i = (size_t)blockIdx.x * 256 + threadIdx.x;
    if (i >= (size_t)N * 32) return;
    int node = (int)(i >> 5);
    float s = dinv[node]; s = s * s;
    float4 v = ((const float4*)nf)[i];
    v.x *= s; v.y *= s; v.z *= s; v.w *= s;
    ((float4*)agg)[i] = v;
}
__global__ __launch_bounds__(256) void k_scatter(
        const int* __restrict__ row, const int* __restrict__ col,
        const float* __restrict__ w, const float* __restrict__ dinv,
        const float* __restrict__ nf, float* __restrict__ agg, int E) {
    int wid = (int)(((size_t)blockIdx.x * blockDim.x + threadIdx.x) >> 6);
    int lane = threadIdx.x & 63;
    if (wid >= E) return;
    int r = row[wid], c = col[wid];
    float nrm = dinv[r] * w[wid] * dinv[c];
    float2 v = ((const float2*)(nf + (size_t)r * 128))[lane];
    float* dst = agg + (size_t)c * 128 + lane * 2;
    atomicAdd(dst, v.x * nrm);
    atomicAdd(dst + 1, v.y * nrm);
}

// legacy f32 VALU GEMM (fallback paths)
__global__ __launch_bounds__(256) void k_gemm2(float* __restrict__ h,
        const float* __restrict__ W, const float* __restrict__ bias,
        float* __restrict__ sums, int N) {
    __shared__ float At[2][32][132];
    __shared__ float Wt[2][32][132];
    int tid = threadIdx.x;
    int tx = tid & 15, ty = tid >> 4;
    int r0 = blockIdx.x * 128;
#define STAGE_A(buf, k0)                                                     \
    _Pragma("unroll")                                                        \
    for (int i = 0; i < 4; ++i) {                                            \
        int idx = tid + 256 * i;                                             \
        int row = idx >> 3, c4 = idx & 7;                                    \
        int gr = r0 + row; if (gr > N - 1) gr = N - 1;                       \
        float4 v = *(const float4*)&h[(size_t)gr * 128 + (k0) + c4 * 4];     \
        At[buf][c4 * 4 + 0][row] = v.x;                                      \
        At[buf][c4 * 4 + 1][row] = v.y;                                      \
        At[buf][c4 * 4 + 2][row] = v.z;                                      \
        At[buf][c4 * 4 + 3][row] = v.w;                                      \
    }
#define STAGE_W(buf, k0)                                                     \
    _Pragma("unroll")                                                        \
    for (int i = 0; i < 4; ++i) {                                            \
        int idx = tid + 256 * i;                                             \
        int kk = idx >> 5, c4 = idx & 31;                                    \
        float4 v = *(const float4*)&W[(size_t)((k0) + kk) * 128 + c4 * 4];   \
        *(float4*)&Wt[buf][kk][c4 * 4] = v;                                  \
    }
    STAGE_A(0, 0)
    STAGE_W(0, 0)
    float acc[8][8] = {};
    for (int t = 0; t < 4; ++t) {
        __syncthreads();
        if (t < 3) {
            int nb = (t + 1) & 1;
            STAGE_A(nb, (t + 1) * 32)
            STAGE_W(nb, (t + 1) * 32)
        }
        int kb = t & 1;
#pragma unroll
        for (int k = 0; k < 32; ++k) {
            float a[8], w[8];
            *(float4*)&a[0] = *(float4*)&At[kb][k][ty * 8];
            *(float4*)&a[4] = *(float4*)&At[kb][k][ty * 8 + 4];
            *(float4*)&w[0] = *(float4*)&Wt[kb][k][tx * 8];
            *(float4*)&w[4] = *(float4*)&Wt[kb][k][tx * 8 + 4];
#pragma unroll
            for (int r = 0; r < 8; ++r)
#pragma unroll
                for (int cc = 0; cc < 8; ++cc)
                    acc[r][cc] += a[r] * w[cc];
        }
    }
    float bv[8];
    *(float4*)&bv[0] = *(const float4*)&bias[tx * 8];
    *(float4*)&bv[4] = *(const float4*)&bias[tx * 8 + 4];
    float s[8] = {}, sq[8] = {};
#pragma unroll
    for (int r = 0; r < 8; ++r) {
        int gr = r0 + ty * 8 + r;
        if (gr < N) {
            float o[8];
#pragma unroll
            for (int cc = 0; cc < 8; ++cc) {
                o[cc] = fmaxf(acc[r][cc] + bv[cc], 0.0f);
                s[cc] += o[cc];
                sq[cc] += o[cc] * o[cc];
            }
            float4* dst = (float4*)&h[(size_t)gr * 128 + tx * 8];
            dst[0] = make_float4(o[0], o[1], o[2], o[3]);
            dst[1] = make_float4(o[4], o[5], o[6], o[7]);
        }
    }
    float* ls = &At[0][0][0];
    __syncthreads();
#pragma unroll
    for (int cc = 0; cc < 8; ++cc) {
        ls[ty * 128 + tx * 8 + cc] = s[cc];
        ls[2048 + ty * 128 + tx * 8 + cc] = sq[cc];
    }
    __syncthreads();
    if (tid < 128) {
        float ssum = 0.f, sqsum = 0.f;
#pragma unroll
        for (int u = 0; u < 16; ++u) {
            ssum += ls[u * 128 + tid];
            sqsum += ls[2048 + u * 128 + tid];
        }
        atomicAdd(&sums[tid], ssum);
        atomicAdd(&sums[128 + tid], sqsum);
    }
#undef STAGE_A
#undef STAGE_W
}

extern "C" void kernel_launch(void* const* d_in, const int* in_sizes, int n_in,
                              void* d_out, int out_size, void* d_ws, size_t ws_size,
                              hipStream_t stream) {
    const float* nf    = (const float*)d_in[0];
    const int*   ei    = (const int*)d_in[1];
    const float* ew    = (const float*)d_in[2];
    const float* W     = (const float*)d_in[3];
    const float* bias  = (const float*)d_in[4];
    const float* gamma = (const float*)d_in[5];
    const float* beta  = (const float*)d_in[6];
    float* out = (float*)d_out;

    const int N = in_sizes[0] / 128;
    const int E = in_sizes[2];
    const int* row = ei;
    const int* col = ei + E;

    int nb_n  = (N + 255) / 256;
    int nb_e  = (E + 255) / 256;
    int nb_w  = (int)(((size_t)N + 3) / 4);
    int nb_v4 = (int)(((size_t)N * 32 + 255) / 256);
    int nbk   = (N + BKT_SZ - 1) >> BKT_BITS;
    int nb_c  = (E + CHUNK - 1) / CHUNK;
    int nconv = (int)(((size_t)N * 16 + 255) / 256);
    size_t n16 = (size_t)N * 16;
    size_t tt_words = (size_t)64 * N > (size_t)E ? (size_t)64 * N : (size_t)E;

    // ---- path-1 layout ----
    float* dinv = (float*)d_ws;                  // N
    int*   ptr  = (int*)d_ws + N;                // N+1
    float* sums = (float*)d_ws + 2 * N + 1;      // 512
    int*   bbase1 = (int*)d_ws + 2 * N + 513;    // nbk+1
    int*   btot   = bbase1 + nbk + 1;            // nbk
    int*   blkoff = btot + nbk;                  // nbk*nb_c
    size_t wt_off = ((size_t)(2 * N + 514 + 2 * nbk) + (size_t)nbk * nb_c + 3) & ~(size_t)3;
    unsigned* wtb = (unsigned*)((int*)d_ws + wt_off);             // 8192
    size_t pk_off = (wt_off + 8192 + 3) & ~(size_t)3;
    unsigned* p1_packed = (unsigned*)((int*)d_ws + pk_off);       // E
    size_t tt_off = (pk_off + (size_t)E + 3) & ~(size_t)3;
    unsigned* p1_tmp = (unsigned*)((int*)d_ws + tt_off);          // tmp(E)/tab(64N)
    unsigned* p1_tab = (unsigned*)((int*)d_ws + tt_off);
    size_t ab_off = (tt_off + tt_words + 3) & ~(size_t)3;
    unsigned* aggb = (unsigned*)((int*)d_ws + ab_off);            // 64N
    size_t need_p1 = (ab_off + (size_t)64 * N) * 4;

    // ---- path-2 layout (4B tmp format) ----
    float* dinv2 = (float*)d_ws;
    int*   ptr2  = (int*)d_ws + N;
    int*   cnt3  = (int*)d_ws + 2 * N + 1;
    float* sums2 = (float*)d_ws + 3 * N + 1;
    int*   bsum2 = (int*)d_ws + 3 * N + 513;
    int*   bbase2 = (int*)d_ws + 3 * N + 1025;
    int*   bcur2  = bbase2 + nbk + 1;
    size_t pk2 = ((size_t)(3 * N + 1026 + 2 * nbk) + 3) & ~(size_t)3;
    unsigned* packed2 = (unsigned*)((int*)d_ws + pk2);            // E
    size_t tt2 = (pk2 + (size_t)E + 3) & ~(size_t)3;
    unsigned* tmp2 = (unsigned*)((int*)d_ws + tt2);
    unsigned* tab2 = (unsigned*)((int*)d_ws + tt2);
    size_t need_full2 = (tt2 + tt_words) * 4;

    // ---- path-3 layout (int2 packed, f32 gather) ----
    int2*  packed3 = (int2*)((int*)d_ws + pk2);                   // 2E
    size_t need_csr3 = (pk2 + (size_t)2 * E) * 4;

    if (nbk <= MAX_BKT && ws_size >= need_p1) {
        // IMPORTANT: tmp aliases tab. passB3 reads tmp records for bucket b
        // from [bbase[b], bbase[b+1]) and writes tab rows for nodes of bucket
        // b at word offsets [node0*64, ...). Since bbase[b] = sum of edges of
        // buckets < b and each bucket has <= 128 nodes -> tab write offset for
        // bucket b is node0*64 = b*8192 words, while tmp reads for bucket b
        // start at bbase[b] (avg b*4096 words, unbounded skew). ALIAS HAZARD:
        // another block's tab writes could clobber unread tmp. To stay safe,
        // tab gets its own region when ws allows; need_p1 already reserves
        // tt_words = max(64N, E) for the shared region, so give tab a
        // DISTINCT region: use aggb-end. Layout here: tmp at tt_off (E words),
        // tab at ab_off + 64N (64N words), aggb at ab_off.
        unsigned* tab_sep = aggb + (size_t)64 * N;
        size_t need_sep = (ab_off + (size_t)128 * N) * 4;
        unsigned* tab_use = (ws_size >= need_sep) ? tab_sep : p1_tab;
        if (ws_size >= need_sep) {
            k_bhist2<<<nb_c, 256, 0, stream>>>(col, blkoff, W, wtb, E, nbk, nb_c);
            k_bscan2a<<<(nbk + 255) / 256, 256, 0, stream>>>(blkoff, btot, nbk, nb_c);
            k_bscan2b<<<1, 1024, 0, stream>>>(btot, bbase1, ptr, sums, nbk, N, E);
            k_passA3<<<nb_c, 256, 0, stream>>>(row, col, ew, blkoff, bbase1, p1_tmp, E, nbk, nb_c);
            k_passB3<<<nbk, 256, 0, stream>>>(p1_tmp, bbase1, nf, tab_use, p1_packed, ptr, dinv, N);
            k_gatherw5<<<nb_w, 256, 0, stream>>>(p1_packed, ptr, dinv, tab_use, aggb, N);
        } else {
            k_bhist2<<<nb_c, 256, 0, stream>>>(col, blkoff, W, wtb, E, nbk, nb_c);
            k_bscan2a<<<(nbk + 255) / 256, 256, 0, stream>>>(blkoff, btot, nbk, nb_c);
            k_bscan2b<<<1, 1024, 0, stream>>>(btot, bbase1, ptr, sums, nbk, N, E);
            k_passA3<<<nb_c, 256, 0, stream>>>(row, col, ew, blkoff, bbase1, p1_tmp, E, nbk, nb_c);
            k_passB2<<<nbk, 256, 0, stream>>>(p1_tmp, bbase1, p1_packed, ptr, dinv, N);
            k_conv2<<<nconv, 256, 0, stream>>>(nf, dinv, (uint4*)p1_tab, N);
            k_gatherw5<<<nb_w, 256, 0, stream>>>(p1_packed, ptr, dinv, p1_tab, aggb, N);
        }
        k_gemm3b<<<(N + 127) / 128, 256, 0, stream>>>(aggb, wtb, bias, sums, N);
        k_bnapplyB2<<<(int)((n16 + 255) / 256), 256, 0, stream>>>(aggb, sums, gamma, beta, out, n16, N);
        return;
    }

    if (nbk <= MAX_BKT && ws_size >= need_full2) {
        k_init0<<<(max(nbk, 512) + 255) / 256, 256, 0, stream>>>(bcur2, sums2, nbk);
        k_bhist<<<nb_c, 256, 0, stream>>>(col, bcur2, E, nbk);
        k_bscan<<<1, 1024, 0, stream>>>(bcur2, bbase2, bcur2, ptr2, nbk, N, E);
        k_passA2<<<nb_c, 256, 0, stream>>>(row, col, ew, bcur2, tmp2, E, nbk);
        k_passB2<<<nbk, 256, 0, stream>>>(tmp2, bbase2, packed2, ptr2, dinv2, N);
        k_conv2<<<nconv, 256, 0, stream>>>(nf, dinv2, (uint4*)tab2, N);
        k_gatherwF<<<nb_w, 256, 0, stream>>>(packed2, ptr2, dinv2, tab2, out, N);
        k_gemm2<<<(N + 127) / 128, 256, 0, stream>>>(out, W, bias, sums2, N);
        k_bnfin<<<1, 128, 0, stream>>>(sums2, gamma, beta, N);
        k_bnapply<<<nb_v4, 256, 0, stream>>>(out, sums2, (size_t)N * 32);
        return;
    }

    if (ws_size >= need_csr3) {
        k_init<<<nb_n, 256, 0, stream>>>(cnt3, sums2, N);
        k_count<<<nb_e, 256, 0, stream>>>(col, cnt3, E);
        kS1<<<nb_n, 256, 0, stream>>>(cnt3, ptr2, bsum2, N);
        kS2<<<1, 512, 0, stream>>>(bsum2, ptr2, nb_n, N);
        kS3<<<nb_n, 256, 0, stream>>>(ptr2, cnt3, bsum2, N);
        k_fill<<<nb_e, 256, 0, stream>>>(row, col, ew, cnt3, packed3, E);
        k_degw<<<nb_w, 256, 0, stream>>>(packed3, ptr2, dinv2, N);
        k_gather<<<nb_w, 256, 0, stream>>>(packed3, ptr2, dinv2, nf, out, N);
        k_gemm2<<<(N + 127) / 128, 256, 0, stream>>>(out, W, bias, sums2, N);
        k_bnfin<<<1, 128, 0, stream>>>(sums2, gamma, beta, N);
        k_bnapply<<<nb_v4, 256, 0, stream>>>(out, sums2, (size_t)N * 32);
        return;
    }

    {
        float* deg = (float*)d_ws;
        float* sm  = (float*)d_ws + N;
        k_initA<<<nb_n, 256, 0, stream>>>(deg, sm, N);
        k_deg<<<nb_e, 256, 0, stream>>>(col, ew, deg, E);
        k_dinv<<<nb_n, 256, 0, stream>>>(deg, N);
        k_self<<<nb_v4, 256, 0, stream>>>(nf, deg, out, N);
        k_scatter<<<(E + 3) / 4, 256, 0, stream>>>(row, col, ew, deg, nf, out, E);
        k_gemm2<<<(N + 127) / 128, 256, 0, stream>>>(out, W, bias, sm, N);
        k_bnfin<<<1, 128, 0, stream>>>(sm, gamma, beta, N);
        k_bnapply<<<nb_v4, 256, 0, stream>>>(out, sm, (size_t)N * 32);
    }
}

// Round 15
// 317.371 us; speedup vs baseline: 2.6843x; 1.0209x over previous
//
#include <hip/hip_runtime.h>
#include <hip/hip_bf16.h>

// GCN layer: h = BN(ReLU(segment_sum(norm * (nf@W))[col] + b))
// FINAL (R8 configuration, proven 317.5us):
// R1: CSR gather.  R2: bf16 table.  R4: block-reservation radix partition.
// R5: fold dinv into tab, single-histogram radix partition.
// R6: MFMA bf16 GEMM, bf16 h intermediate.
// R8: zero-waste wave-per-node gather (uncond 4-deep main, 2-deep mid,
//     exec-masked tail), bf16-bits weight encoding, 4-byte tmp records.
// R9-R13 post-mortems: quarter/4-deep gather restructures, no-W-stage gemm,
// merged scans, and kernel fusions ALL regressed -- this config is the
// empirical optimum; gather pinned at ~107us (random-256B L2/L3 ceiling).
// R14: fix duplicate k_passB2 definition (compile error only).

#define BKT_BITS 7
#define BKT_SZ 128
#define MAX_BKT 1024        // N <= 131072 (row fits 17 bits)
#define CHUNK 8192

typedef __attribute__((ext_vector_type(8))) short bf16x8;
typedef __attribute__((ext_vector_type(4))) float f32x4;

__device__ __forceinline__ unsigned bf16rn(float f) {
    unsigned x = __float_as_uint(f);
    return (x + 0x7fffu + ((x >> 16) & 1u)) >> 16;
}
__device__ __forceinline__ float bflo(unsigned u) { return __uint_as_float(u << 16); }
__device__ __forceinline__ float bfhi(unsigned u) { return __uint_as_float(u & 0xffff0000u); }

// ---------------- path 1: single-histogram radix partition ----------------
__global__ __launch_bounds__(256) void k_bhist2(const int* __restrict__ col,
        int* __restrict__ blkoff, int E, int nb, int nbc) {
    __shared__ int h[MAX_BKT];
    for (int i = threadIdx.x; i < nb; i += 256) h[i] = 0;
    __syncthreads();
    int base = blockIdx.x * CHUNK, lim = min(base + CHUNK, E);
    for (int e = base + threadIdx.x; e < lim; e += 256)
        atomicAdd(&h[col[e] >> BKT_BITS], 1);
    __syncthreads();
    for (int i = threadIdx.x; i < nb; i += 256)
        blkoff[(size_t)i * nbc + blockIdx.x] = h[i];
}

__global__ void k_bscan2a(int* __restrict__ blkoff, int* __restrict__ btot,
                          int nb, int nbc) {
    int b = blockIdx.x * 256 + threadIdx.x;
    if (b >= nb) return;
    int* p = blkoff + (size_t)b * nbc;
    int run = 0;
#pragma unroll 4
    for (int i = 0; i < nbc; ++i) { int c = p[i]; p[i] = run; run += c; }
    btot[b] = run;
}

__global__ __launch_bounds__(1024) void k_bscan2b(const int* __restrict__ btot,
        int* __restrict__ bbase, int* __restrict__ ptr, float* __restrict__ sums,
        int nb, int N, int E) {
    __shared__ int ls[1024];
    int t = threadIdx.x;
    int v = (t < nb) ? btot[t] : 0;
    ls[t] = v;
    __syncthreads();
    for (int off = 1; off < 1024; off <<= 1) {
        int u = (t >= off) ? ls[t - off] : 0;
        __syncthreads();
        ls[t] += u;
        __syncthreads();
    }
    if (t < nb) bbase[t] = ls[t] - v;
    if (t == nb - 1) bbase[nb] = ls[t];
    if (t == 0) ptr[N] = E;
    if (t < 512) sums[t] = 0.0f;
}

// scatter into bucket-grouped tmp: rec = row17<<15 | col7<<8 | w8
__global__ __launch_bounds__(256) void k_passA3(
        const int* __restrict__ row, const int* __restrict__ col,
        const float* __restrict__ w, const int* __restrict__ blkoff,
        const int* __restrict__ bbase, unsigned* __restrict__ tmp,
        int E, int nb, int nbc) {
    __shared__ int cur[MAX_BKT];
    for (int i = threadIdx.x; i < nb; i += 256)
        cur[i] = bbase[i] + blkoff[(size_t)i * nbc + blockIdx.x];
    __syncthreads();
    int base = blockIdx.x * CHUNK, lim = min(base + CHUNK, E);
    for (int e = base + threadIdx.x; e < lim; e += 256) {
        int c = col[e];
        int q8 = (int)(w[e] * 256.0f + 0.5f);
        if (q8 > 255) q8 = 255;
        unsigned rec = ((unsigned)row[e] << 15) | ((unsigned)(c & 127) << 8) | (unsigned)q8;
        int pos = atomicAdd(&cur[c >> BKT_BITS], 1);
        tmp[pos] = rec;
    }
}

// pass B: per-node offsets in LDS, place edges as row17|wbf15
// (wbf15 = bf16 bits of w*dinv[col], <0x8000), fused degree -> dinv.
__global__ __launch_bounds__(256) void k_passB2(
        const unsigned* __restrict__ tmp, const int* __restrict__ bbase,
        unsigned* __restrict__ packed, int* __restrict__ ptr,
        float* __restrict__ dinv, int N) {
    __shared__ int hcnt[BKT_SZ];
    __shared__ int wsumi[BKT_SZ];
    __shared__ int cur[BKT_SZ];
    __shared__ float dcl[BKT_SZ];
    int b = blockIdx.x;
    int t = threadIdx.x;
    if (t < BKT_SZ) { hcnt[t] = 0; wsumi[t] = 0; }
    __syncthreads();
    int beg = bbase[b], end = bbase[b + 1];
    for (int k = beg + t; k < end; k += 256) {
        unsigned p = tmp[k];
        int li = (p >> 8) & 127;
        atomicAdd(&hcnt[li], 1);
        atomicAdd(&wsumi[li], (int)(p & 255u));
    }
    __syncthreads();
    if (t < BKT_SZ) cur[t] = hcnt[t];
    __syncthreads();
    for (int off = 1; off < BKT_SZ; off <<= 1) {
        int v = (t < BKT_SZ && t >= off) ? cur[t - off] : 0;
        __syncthreads();
        if (t < BKT_SZ) cur[t] += v;
        __syncthreads();
    }
    if (t < BKT_SZ) {
        int p = beg + cur[t] - hcnt[t];
        cur[t] = p;
        float d = 1.0f + (float)wsumi[t] * (1.0f / 256.0f);
        float dc = rsqrtf(d);
        dcl[t] = dc;
        int n = (b << BKT_BITS) + t;
        if (n < N) { ptr[n] = p; dinv[n] = dc; }
    }
    __syncthreads();
    for (int k = beg + t; k < end; k += 256) {
        unsigned p = tmp[k];
        int li = (p >> 8) & 127;
        int pos = atomicAdd(&cur[li], 1);
        float fw = (float)(p & 255u) * (1.0f / 256.0f) * dcl[li];
        unsigned wb = bf16rn(fw) & 0x7FFFu;
        packed[pos] = ((p >> 15) << 15) | wb;
    }
}

// tab[r] = bf16(nf[r] * dinv[r])
__global__ void k_conv2(const float* __restrict__ nf, const float* __restrict__ dinv,
                        uint4* __restrict__ tab, int N) {
    size_t i = (size_t)blockIdx.x * 256 + threadIdx.x;
    if (i >= (size_t)N * 16) return;
    int n = (int)(i >> 4);
    float dv = dinv[n];
    const float4* src = (const float4*)nf + 2 * i;
    float4 a = src[0], b = src[1];
    uint4 r;
    r.x = bf16rn(a.x * dv) | (bf16rn(a.y * dv) << 16);
    r.y = bf16rn(a.z * dv) | (bf16rn(a.w * dv) << 16);
    r.z = bf16rn(b.x * dv) | (bf16rn(b.y * dv) << 16);
    r.w = bf16rn(b.z * dv) | (bf16rn(b.w * dv) << 16);
    tab[i] = r;
}

// WT[j][k2] = bf16(W[2k2][j]) | bf16(W[2k2+1][j])<<16  (8192 words)
__global__ void k_convW(const float* __restrict__ W, unsigned* __restrict__ WT) {
    int i = blockIdx.x * 256 + threadIdx.x;
    if (i >= 128 * 64) return;
    int j = i >> 6, w = i & 63;
    float a = W[(size_t)(2 * w) * 128 + j];
    float b = W[(size_t)(2 * w + 1) * 128 + j];
    WT[i] = bf16rn(a) | (bf16rn(b) << 16);
}

#define EDGE_FMA(aX, nX, tX)                                     \
    aX[0] += nX * bflo(tX.x); aX[1] += nX * bfhi(tX.x);          \
    aX[2] += nX * bflo(tX.y); aX[3] += nX * bfhi(tX.y);          \
    aX[4] += nX * bflo(tX.z); aX[5] += nX * bfhi(tX.z);          \
    aX[6] += nX * bflo(tX.w); aX[7] += nX * bfhi(tX.w);

// gather: wave per node; uncond 4-deep main, 2-deep mid, exec-masked tail.
// packed rec = row17|wbf15 (w*dinv[col] as bf16 bits); dinv[row] folded in tab.
__global__ __launch_bounds__(256) void k_gatherw5(
        const unsigned* __restrict__ packed, const int* __restrict__ ptr,
        const float* __restrict__ dinv, const unsigned* __restrict__ tab,
        unsigned* __restrict__ aggb, int N) {
    int wid = (int)(((size_t)blockIdx.x * 256 + threadIdx.x) >> 6);
    int lane = threadIdx.x & 63;
    if (wid >= N) return;
    int beg = ptr[wid], end = ptr[wid + 1];
    float dc = dinv[wid];
    int q = lane >> 4;       // edge slot
    int fl = lane & 15;      // features [8*fl, 8*fl+8)
    float a0[8] = {}, a1[8] = {}, a2[8] = {}, a3[8] = {};
    int k = beg;
    for (; k + 16 <= end; k += 16) {
        unsigned p0 = packed[k + q];
        unsigned p1 = packed[k + 4 + q];
        unsigned p2 = packed[k + 8 + q];
        unsigned p3 = packed[k + 12 + q];
        uint4 t0 = *(const uint4*)(tab + (size_t)(p0 >> 15) * 64 + fl * 4);
        uint4 t1 = *(const uint4*)(tab + (size_t)(p1 >> 15) * 64 + fl * 4);
        uint4 t2 = *(const uint4*)(tab + (size_t)(p2 >> 15) * 64 + fl * 4);
        uint4 t3 = *(const uint4*)(tab + (size_t)(p3 >> 15) * 64 + fl * 4);
        float n0 = bflo(p0 & 0x7FFFu);
        float n1 = bflo(p1 & 0x7FFFu);
        float n2 = bflo(p2 & 0x7FFFu);
        float n3 = bflo(p3 & 0x7FFFu);
        EDGE_FMA(a0, n0, t0)
        EDGE_FMA(a1, n1, t1)
        EDGE_FMA(a2, n2, t2)
        EDGE_FMA(a3, n3, t3)
    }
    if (k + 8 <= end) {
        unsigned p0 = packed[k + q];
        unsigned p1 = packed[k + 4 + q];
        uint4 t0 = *(const uint4*)(tab + (size_t)(p0 >> 15) * 64 + fl * 4);
        uint4 t1 = *(const uint4*)(tab + (size_t)(p1 >> 15) * 64 + fl * 4);
        float n0 = bflo(p0 & 0x7FFFu);
        float n1 = bflo(p1 & 0x7FFFu);
        EDGE_FMA(a0, n0, t0)
        EDGE_FMA(a1, n1, t1)
        k += 8;
    }
    for (; k < end; k += 4) {
        int i0 = k + q;
        if (i0 < end) {      // exec-masked: no loads from invalid lanes
            unsigned p0 = packed[i0];
            uint4 t0 = *(const uint4*)(tab + (size_t)(p0 >> 15) * 64 + fl * 4);
            float n0 = bflo(p0 & 0x7FFFu);
            EDGE_FMA(a0, n0, t0)
        }
    }
#pragma unroll
    for (int j = 0; j < 8; ++j) {
        float s = (a0[j] + a1[j]) + (a2[j] + a3[j]);
        s += __shfl_xor(s, 16);
        s += __shfl_xor(s, 32);
        a0[j] = s;
    }
    if (q == 0) {
        uint4 t = *(const uint4*)(tab + (size_t)wid * 64 + fl * 4);
        EDGE_FMA(a0, dc, t)   // self: dc*tab[c]
        uint4 r;
        r.x = bf16rn(a0[0]) | (bf16rn(a0[1]) << 16);
        r.y = bf16rn(a0[2]) | (bf16rn(a0[3]) << 16);
        r.z = bf16rn(a0[4]) | (bf16rn(a0[5]) << 16);
        r.w = bf16rn(a0[6]) | (bf16rn(a0[7]) << 16);
        *(uint4*)(aggb + (size_t)wid * 64 + fl * 4) = r;
    }
}

// gather -> f32 rows into out (path-2 fallback; same packed format)
__global__ __launch_bounds__(256) void k_gatherwF(
        const unsigned* __restrict__ packed, const int* __restrict__ ptr,
        const float* __restrict__ dinv, const unsigned* __restrict__ tab,
        float* __restrict__ out, int N) {
    int wid = (int)(((size_t)blockIdx.x * 256 + threadIdx.x) >> 6);
    int lane = threadIdx.x & 63;
    if (wid >= N) return;
    int beg = ptr[wid], end = ptr[wid + 1];
    float dc = dinv[wid];
    int q = lane >> 4;
    int fl = lane & 15;
    float a0[8] = {}, a1[8] = {};
    int k = beg;
    for (; k + 8 <= end; k += 8) {
        unsigned p0 = packed[k + q];
        unsigned p1 = packed[k + 4 + q];
        uint4 t0 = *(const uint4*)(tab + (size_t)(p0 >> 15) * 64 + fl * 4);
        uint4 t1 = *(const uint4*)(tab + (size_t)(p1 >> 15) * 64 + fl * 4);
        float n0 = bflo(p0 & 0x7FFFu);
        float n1 = bflo(p1 & 0x7FFFu);
        EDGE_FMA(a0, n0, t0)
        EDGE_FMA(a1, n1, t1)
    }
    for (; k < end; k += 4) {
        int i0 = k + q;
        if (i0 < end) {
            unsigned p0 = packed[i0];
            uint4 t0 = *(const uint4*)(tab + (size_t)(p0 >> 15) * 64 + fl * 4);
            float n0 = bflo(p0 & 0x7FFFu);
            EDGE_FMA(a0, n0, t0)
        }
    }
#pragma unroll
    for (int j = 0; j < 8; ++j) {
        float s = a0[j] + a1[j];
        s += __shfl_xor(s, 16);
        s += __shfl_xor(s, 32);
        a0[j] = s;
    }
    if (q == 0) {
        uint4 t = *(const uint4*)(tab + (size_t)wid * 64 + fl * 4);
        EDGE_FMA(a0, dc, t)
        float4* dst = (float4*)(out + (size_t)wid * 128 + fl * 8);
        dst[0] = make_float4(a0[0], a0[1], a0[2], a0[3]);
        dst[1] = make_float4(a0[4], a0[5], a0[6], a0[7]);
    }
}

// MFMA bf16 GEMM: aggb (bf16) -> h = relu(aggb@W+b) -> aggb (bf16, in place);
// fused BN partial sums.
__global__ __launch_bounds__(256) void k_gemm3b(
        unsigned* aggb, const unsigned* __restrict__ WT,
        const float* __restrict__ bias, float* __restrict__ sums, int N) {
    __shared__ unsigned A_l[128][68];
    __shared__ unsigned W_l[128][68];
    __shared__ float bs[256];
    int tid = threadIdx.x;
    int r0 = blockIdx.x * 128;
    bs[tid] = 0.0f;
    {
        int j = tid >> 1, h = tid & 1;
        const uint4* src = (const uint4*)(WT + j * 64 + h * 32);
#pragma unroll
        for (int i = 0; i < 8; ++i)
            *(uint4*)&W_l[j][h * 32 + i * 4] = src[i];
    }
    {
        int j = tid >> 1, h = tid & 1;
        int gr = r0 + j;
        if (gr < N) {
            const uint4* src = (const uint4*)(aggb + (size_t)gr * 64 + h * 32);
#pragma unroll
            for (int i = 0; i < 8; ++i)
                *(uint4*)&A_l[j][h * 32 + i * 4] = src[i];
        } else {
            uint4 z = {0, 0, 0, 0};
#pragma unroll
            for (int i = 0; i < 8; ++i)
                *(uint4*)&A_l[j][h * 32 + i * 4] = z;
        }
    }
    __syncthreads();

    int wv = tid >> 6, l = tid & 63;
    int lr = l & 15, lk = l >> 4;
    f32x4 acc[2][8] = {};
#pragma unroll
    for (int ks = 0; ks < 4; ++ks) {
        bf16x8 a0 = *(bf16x8*)&A_l[wv * 32 + lr][ks * 16 + lk * 4];
        bf16x8 a1 = *(bf16x8*)&A_l[wv * 32 + 16 + lr][ks * 16 + lk * 4];
#pragma unroll
        for (int nt = 0; nt < 8; ++nt) {
            bf16x8 b = *(bf16x8*)&W_l[nt * 16 + lr][ks * 16 + lk * 4];
            acc[0][nt] = __builtin_amdgcn_mfma_f32_16x16x32_bf16(a0, b, acc[0][nt], 0, 0, 0);
            acc[1][nt] = __builtin_amdgcn_mfma_f32_16x16x32_bf16(a1, b, acc[1][nt], 0, 0, 0);
        }
    }

    unsigned short* ab = (unsigned short*)aggb;
#pragma unroll
    for (int nt = 0; nt < 8; ++nt) {
        int colc = nt * 16 + lr;
        float bc = bias[colc];
        float s = 0.0f, sq = 0.0f;
#pragma unroll
        for (int ms = 0; ms < 2; ++ms) {
#pragma unroll
            for (int p = 0; p < 4; ++p) {
                int rrow = r0 + wv * 32 + ms * 16 + lk * 4 + p;
                float v = fmaxf(acc[ms][nt][p] + bc, 0.0f);
                if (rrow < N) {
                    ab[(size_t)rrow * 128 + colc] = (unsigned short)bf16rn(v);
                    s += v;
                    sq += v * v;
                }
            }
        }
        s += __shfl_xor(s, 16);  s += __shfl_xor(s, 32);
        sq += __shfl_xor(sq, 16); sq += __shfl_xor(sq, 32);
        if (l < 16) {
            atomicAdd(&bs[colc], s);
            atomicAdd(&bs[128 + colc], sq);
        }
    }
    __syncthreads();
    if (tid < 128) {
        atomicAdd(&sums[tid], bs[tid]);
        atomicAdd(&sums[128 + tid], bs[128 + tid]);
    }
}

__global__ void k_bnfin(float* __restrict__ sums, const float* __restrict__ gamma,
                        const float* __restrict__ beta, int N) {
    int j = threadIdx.x;
    float inv_n = 1.0f / (float)N;
    float mean = sums[j] * inv_n;
    float var = sums[128 + j] * inv_n - mean * mean;
    float sc = rsqrtf(var + 1e-5f) * gamma[j];
    sums[256 + j] = sc;
    sums[384 + j] = beta[j] - mean * sc;
}

// BN apply: bf16 aggb -> f32 out
__global__ void k_bnapplyB(const unsigned* __restrict__ aggb,
                           const float* __restrict__ sums,
                           float* __restrict__ out, size_t n16) {
    size_t i = (size_t)blockIdx.x * 256 + threadIdx.x;
    if (i >= n16) return;
    int g = (int)(i & 15);
    uint4 v = ((const uint4*)aggb)[i];
    float4 sc0 = *(const float4*)(sums + 256 + g * 8);
    float4 sc1 = *(const float4*)(sums + 256 + g * 8 + 4);
    float4 sh0 = *(const float4*)(sums + 384 + g * 8);
    float4 sh1 = *(const float4*)(sums + 384 + g * 8 + 4);
    float4 o0, o1;
    o0.x = bflo(v.x) * sc0.x + sh0.x;
    o0.y = bfhi(v.x) * sc0.y + sh0.y;
    o0.z = bflo(v.y) * sc0.z + sh0.z;
    o0.w = bfhi(v.y) * sc0.w + sh0.w;
    o1.x = bflo(v.z) * sc1.x + sh1.x;
    o1.y = bfhi(v.z) * sc1.y + sh1.y;
    o1.z = bflo(v.w) * sc1.z + sh1.z;
    o1.w = bfhi(v.w) * sc1.w + sh1.w;
    ((float4*)out)[2 * i] = o0;
    ((float4*)out)[2 * i + 1] = o1;
}

__global__ void k_bnapply(float* __restrict__ h, const float* __restrict__ sums, size_t n4) {
    size_t i = (size_t)blockIdx.x * 256 + threadIdx.x;
    if (i >= n4) return;
    int j4 = (int)(i & 31);
    float4 v = ((float4*)h)[i];
    float4 sc = ((const float4*)(sums + 256))[j4];
    float4 sh = ((const float4*)(sums + 384))[j4];
    v.x = v.x * sc.x + sh.x;
    v.y = v.y * sc.y + sh.y;
    v.z = v.z * sc.z + sh.z;
    v.w = v.w * sc.w + sh.w;
    ((float4*)h)[i] = v;
}

// ---------------- path 2 (reservation partition, 4B tmp format) ----------
__global__ void k_init0(int* __restrict__ bcnt, float* __restrict__ sums, int nb) {
    int i = blockIdx.x * 256 + threadIdx.x;
    if (i < nb) bcnt[i] = 0;
    if (blockIdx.x == 0 && threadIdx.x < 512) sums[threadIdx.x] = 0.0f;
}
__global__ __launch_bounds__(256) void k_bhist(const int* __restrict__ col,
                                               int* __restrict__ bcnt, int E, int nb) {
    __shared__ int h[MAX_BKT];
    for (int i = threadIdx.x; i < nb; i += 256) h[i] = 0;
    __syncthreads();
    int base = blockIdx.x * CHUNK, lim = min(base + CHUNK, E);
    for (int e = base + threadIdx.x; e < lim; e += 256)
        atomicAdd(&h[col[e] >> BKT_BITS], 1);
    __syncthreads();
    for (int i = threadIdx.x; i < nb; i += 256) {
        int c = h[i];
        if (c) atomicAdd(&bcnt[i], c);
    }
}
__global__ __launch_bounds__(1024) void k_bscan(const int* __restrict__ bcnt,
        int* __restrict__ bbase, int* __restrict__ bcur,
        int* __restrict__ ptr, int nb, int N, int E) {
    __shared__ int ls[1024];
    int t = threadIdx.x;
    int v = (t < nb) ? bcnt[t] : 0;
    ls[t] = v;
    __syncthreads();
    for (int off = 1; off < 1024; off <<= 1) {
        int u = (t >= off) ? ls[t - off] : 0;
        __syncthreads();
        ls[t] += u;
        __syncthreads();
    }
    if (t < nb) {
        int ex = ls[t] - v;
        bbase[t] = ex;
        bcur[t] = ex;
    }
    if (t == nb - 1) bbase[nb] = ls[t];
    if (t == 0) ptr[N] = E;
}
__global__ __launch_bounds__(256) void k_passA2(
        const int* __restrict__ row, const int* __restrict__ col,
        const float* __restrict__ w, int* __restrict__ bcur,
        unsigned* __restrict__ tmp, int E, int nb) {
    __shared__ int h[MAX_BKT];
    for (int i = threadIdx.x; i < nb; i += 256) h[i] = 0;
    __syncthreads();
    int base = blockIdx.x * CHUNK, lim = min(base + CHUNK, E);
    for (int e = base + threadIdx.x; e < lim; e += 256)
        atomicAdd(&h[col[e] >> BKT_BITS], 1);
    __syncthreads();
    for (int i = threadIdx.x; i < nb; i += 256) {
        int c = h[i];
        if (c) h[i] = atomicAdd(&bcur[i], c);
    }
    __syncthreads();
    for (int e = base + threadIdx.x; e < lim; e += 256) {
        int c = col[e];
        int q8 = (int)(w[e] * 256.0f + 0.5f);
        if (q8 > 255) q8 = 255;
        unsigned rec = ((unsigned)row[e] << 15) | ((unsigned)(c & 127) << 8) | (unsigned)q8;
        int pos = atomicAdd(&h[c >> BKT_BITS], 1);
        tmp[pos] = rec;
    }
}

// ---------------- path 3/4 fallbacks (full precision, independent) --------
__global__ void k_init(int* __restrict__ cnt, float* __restrict__ sums, int N) {
    int i = blockIdx.x * 256 + threadIdx.x;
    if (i < N) cnt[i] = 0;
    if (blockIdx.x == 0 && threadIdx.x < 512) sums[threadIdx.x] = 0.0f;
}
__global__ void k_count(const int* __restrict__ col, int* __restrict__ cnt, int E) {
    int e = blockIdx.x * 256 + threadIdx.x;
    if (e < E) atomicAdd(&cnt[col[e]], 1);
}
__global__ __launch_bounds__(256) void kS1(const int* __restrict__ cnt,
                                           int* __restrict__ ptr,
                                           int* __restrict__ bsum, int N) {
    __shared__ int ls[256];
    int t = threadIdx.x, i = blockIdx.x * 256 + t;
    int v = (i < N) ? cnt[i] : 0;
    ls[t] = v;
    __syncthreads();
    for (int off = 1; off < 256; off <<= 1) {
        int u = (t >= off) ? ls[t - off] : 0;
        __syncthreads();
        ls[t] += u;
        __syncthreads();
    }
    if (i < N) ptr[i] = ls[t] - v;
    if (t == 255) bsum[blockIdx.x] = ls[255];
}
__global__ __launch_bounds__(512) void kS2(int* __restrict__ bsum,
                                           int* __restrict__ ptr, int NB, int N) {
    __shared__ int ls[512];
    int t = threadIdx.x;
    int chunk = (NB + 511) / 512;
    int b = t * chunk, e = min(b + chunk, NB);
    int s = 0;
    for (int i = b; i < e; ++i) s += bsum[i];
    ls[t] = s;
    __syncthreads();
    for (int off = 1; off < 512; off <<= 1) {
        int u = (t >= off) ? ls[t - off] : 0;
        __syncthreads();
        ls[t] += u;
        __syncthreads();
    }
    int run = ls[t] - s;
    for (int i = b; i < e; ++i) { int c = bsum[i]; bsum[i] = run; run += c; }
    if (t == 511) ptr[N] = ls[511];
}
__global__ void kS3(int* __restrict__ ptr, int* __restrict__ cnt,
                    const int* __restrict__ bsum, int N) {
    int i = blockIdx.x * 256 + threadIdx.x;
    if (i >= N) return;
    int p = ptr[i] + bsum[blockIdx.x];
    ptr[i] = p;
    cnt[i] = p;
}
__global__ void k_fill(const int* __restrict__ row, const int* __restrict__ col,
                       const float* __restrict__ w, int* __restrict__ cursor,
                       int2* __restrict__ packed, int E) {
    int e = blockIdx.x * 256 + threadIdx.x;
    if (e < E) {
        int pos = atomicAdd(&cursor[col[e]], 1);
        packed[pos] = make_int2(row[e], __float_as_int(w[e]));
    }
}
__global__ __launch_bounds__(256) void k_degw(const int2* __restrict__ packed,
                                              const int* __restrict__ ptr,
                                              float* __restrict__ dinv, int N) {
    int wid = (int)(((size_t)blockIdx.x * 256 + threadIdx.x) >> 6);
    int lane = threadIdx.x & 63;
    if (wid >= N) return;
    int beg = ptr[wid], end = ptr[wid + 1];
    float s = 0.0f;
    for (int k = beg + lane; k < end; k += 64) s += __int_as_float(packed[k].y);
#pragma unroll
    for (int off = 32; off; off >>= 1) s += __shfl_xor(s, off);
    if (lane == 0) {
        float d = 1.0f + s;
        dinv[wid] = d > 0.0f ? rsqrtf(d) : 0.0f;
    }
}
__global__ __launch_bounds__(256) void k_gather(
        const int2* __restrict__ packed, const int* __restrict__ ptr,
        const float* __restrict__ dinv, const float* __restrict__ nf,
        float* __restrict__ out, int N) {
    int wid = (int)(((size_t)blockIdx.x * 256 + threadIdx.x) >> 6);
    int lane = threadIdx.x & 63;
    if (wid >= N) return;
    int c = wid;
    int beg = ptr[c], end = ptr[c + 1];
    float dc = dinv[c];
    int half = lane >> 5;
    int fl = lane & 31;
    float4 acc = {0.f, 0.f, 0.f, 0.f};
    for (int k = beg; k < end; k += 2) {
        int idx = k + half;
        bool v = idx < end;
        int2 p = packed[v ? idx : beg];
        float nrm = v ? dc * __int_as_float(p.y) * dinv[p.x] : 0.0f;
        float4 x = ((const float4*)(nf + (size_t)p.x * 128))[fl];
        acc.x += nrm * x.x; acc.y += nrm * x.y;
        acc.z += nrm * x.z; acc.w += nrm * x.w;
    }
    acc.x += __shfl_xor(acc.x, 32);
    acc.y += __shfl_xor(acc.y, 32);
    acc.z += __shfl_xor(acc.z, 32);
    acc.w += __shfl_xor(acc.w, 32);
    if (half == 0) {
        float s2 = dc * dc;
        float4 sf = ((const float4*)(nf + (size_t)c * 128))[fl];
        acc.x += s2 * sf.x; acc.y += s2 * sf.y;
        acc.z += s2 * sf.z; acc.w += s2 * sf.w;
        ((float4*)(out + (size_t)c * 128))[fl] = acc;
    }
}
__global__ void k_initA(float* __restrict__ deg, float* __restrict__ sums, int N) {
    int i = blockIdx.x * 256 + threadIdx.x;
    if (i < N) deg[i] = 1.0f;
    if (blockIdx.x == 0 && threadIdx.x < 512) sums[threadIdx.x] = 0.0f;
}
__global__ void k_deg(const int* __restrict__ col, const float* __restrict__ w,
                      float* __restrict__ deg, int E) {
    int e = blockIdx.x * 256 + threadIdx.x;
    if (e < E) atomicAdd(&deg[col[e]], w[e]);
}
__global__ void k_dinv(float* __restrict__ deg, int N) {
    int i = blockIdx.x * 256 + threadIdx.x;
    if (i < N) { float d = deg[i]; deg[i] = d > 0.0f ? rsqrtf(d) : 0.0f; }
}
__global__ void k_self(const float* __restrict__ nf, const float* __restrict__ dinv,
                       float* __restrict__ agg, int N) {
    size_t i = (size_t)blockIdx.x * 256 + threadIdx.x;
    if (i >= (size_t)N * 32) return;
    int node = (int)(i >> 5);
    float s = dinv[node]; s = s * s;
    float4 v = ((const float4*)nf)[i];
    v.x *= s; v.y *= s; v.z *= s; v.w *= s;
    ((float4*)agg)[i] = v;
}
__global__ __launch_bounds__(256) void k_scatter(
        const int* __restrict__ row, const int* __restrict__ col,
        const float* __restrict__ w, const float* __restrict__ dinv,
        const float* __restrict__ nf, float* __restrict__ agg, int E) {
    int wid = (int)(((size_t)blockIdx.x * blockDim.x + threadIdx.x) >> 6);
    int lane = threadIdx.x & 63;
    if (wid >= E) return;
    int r = row[wid], c = col[wid];
    float nrm = dinv[r] * w[wid] * dinv[c];
    float2 v = ((const float2*)(nf + (size_t)r * 128))[lane];
    float* dst = agg + (size_t)c * 128 + lane * 2;
    atomicAdd(dst, v.x * nrm);
    atomicAdd(dst + 1, v.y * nrm);
}

// legacy f32 VALU GEMM (fallback paths)
__global__ __launch_bounds__(256) void k_gemm2(float* __restrict__ h,
        const float* __restrict__ W, const float* __restrict__ bias,
        float* __restrict__ sums, int N) {
    __shared__ float At[2][32][132];
    __shared__ float Wt[2][32][132];
    int tid = threadIdx.x;
    int tx = tid & 15, ty = tid >> 4;
    int r0 = blockIdx.x * 128;
#define STAGE_A(buf, k0)                                                     \
    _Pragma("unroll")                                                        \
    for (int i = 0; i < 4; ++i) {                                            \
        int idx = tid + 256 * i;                                             \
        int row = idx >> 3, c4 = idx & 7;                                    \
        int gr = r0 + row; if (gr > N - 1) gr = N - 1;                       \
        float4 v = *(const float4*)&h[(size_t)gr * 128 + (k0) + c4 * 4];     \
        At[buf][c4 * 4 + 0][row] = v.x;                                      \
        At[buf][c4 * 4 + 1][row] = v.y;                                      \
        At[buf][c4 * 4 + 2][row] = v.z;                                      \
        At[buf][c4 * 4 + 3][row] = v.w;                                      \
    }
#define STAGE_W(buf, k0)                                                     \
    _Pragma("unroll")                                                        \
    for (int i = 0; i < 4; ++i) {                                            \
        int idx = tid + 256 * i;                                             \
        int kk = idx >> 5, c4 = idx & 31;                                    \
        float4 v = *(const float4*)&W[(size_t)((k0) + kk) * 128 + c4 * 4];   \
        *(float4*)&Wt[buf][kk][c4 * 4] = v;                                  \
    }
    STAGE_A(0, 0)
    STAGE_W(0, 0)
    float acc[8][8] = {};
    for (int t = 0; t < 4; ++t) {
        __syncthreads();
        if (t < 3) {
            int nb = (t + 1) & 1;
            STAGE_A(nb, (t + 1) * 32)
            STAGE_W(nb, (t + 1) * 32)
        }
        int kb = t & 1;
#pragma unroll
        for (int k = 0; k < 32; ++k) {
            float a[8], w[8];
            *(float4*)&a[0] = *(float4*)&At[kb][k][ty * 8];
            *(float4*)&a[4] = *(float4*)&At[kb][k][ty * 8 + 4];
            *(float4*)&w[0] = *(float4*)&Wt[kb][k][tx * 8];
            *(float4*)&w[4] = *(float4*)&Wt[kb][k][tx * 8 + 4];
#pragma unroll
            for (int r = 0; r < 8; ++r)
#pragma unroll
                for (int cc = 0; cc < 8; ++cc)
                    acc[r][cc] += a[r] * w[cc];
        }
    }
    float bv[8];
    *(float4*)&bv[0] = *(const float4*)&bias[tx * 8];
    *(float4*)&bv[4] = *(const float4*)&bias[tx * 8 + 4];
    float s[8] = {}, sq[8] = {};
#pragma unroll
    for (int r = 0; r < 8; ++r) {
        int gr = r0 + ty * 8 + r;
        if (gr < N) {
            float o[8];
#pragma unroll
            for (int cc = 0; cc < 8; ++cc) {
                o[cc] = fmaxf(acc[r][cc] + bv[cc], 0.0f);
                s[cc] += o[cc];
                sq[cc] += o[cc] * o[cc];
            }
            float4* dst = (float4*)&h[(size_t)gr * 128 + tx * 8];
            dst[0] = make_float4(o[0], o[1], o[2], o[3]);
            dst[1] = make_float4(o[4], o[5], o[6], o[7]);
        }
    }
    float* ls = &At[0][0][0];
    __syncthreads();
#pragma unroll
    for (int cc = 0; cc < 8; ++cc) {
        ls[ty * 128 + tx * 8 + cc] = s[cc];
        ls[2048 + ty * 128 + tx * 8 + cc] = sq[cc];
    }
    __syncthreads();
    if (tid < 128) {
        float ssum = 0.f, sqsum = 0.f;
#pragma unroll
        for (int u = 0; u < 16; ++u) {
            ssum += ls[u * 128 + tid];
            sqsum += ls[2048 + u * 128 + tid];
        }
        atomicAdd(&sums[tid], ssum);
        atomicAdd(&sums[128 + tid], sqsum);
    }
#undef STAGE_A
#undef STAGE_W
}

extern "C" void kernel_launch(void* const* d_in, const int* in_sizes, int n_in,
                              void* d_out, int out_size, void* d_ws, size_t ws_size,
                              hipStream_t stream) {
    const float* nf    = (const float*)d_in[0];
    const int*   ei    = (const int*)d_in[1];
    const float* ew    = (const float*)d_in[2];
    const float* W     = (const float*)d_in[3];
    const float* bias  = (const float*)d_in[4];
    const float* gamma = (const float*)d_in[5];
    const float* beta  = (const float*)d_in[6];
    float* out = (float*)d_out;

    const int N = in_sizes[0] / 128;
    const int E = in_sizes[2];
    const int* row = ei;
    const int* col = ei + E;

    int nb_n  = (N + 255) / 256;
    int nb_e  = (E + 255) / 256;
    int nb_w  = (int)(((size_t)N + 3) / 4);
    int nb_v4 = (int)(((size_t)N * 32 + 255) / 256);
    int nbk   = (N + BKT_SZ - 1) >> BKT_BITS;
    int nb_c  = (E + CHUNK - 1) / CHUNK;
    int nconv = (int)(((size_t)N * 16 + 255) / 256);
    size_t n16 = (size_t)N * 16;
    size_t tt_words = (size_t)64 * N > (size_t)E ? (size_t)64 * N : (size_t)E;

    // ---- path-1 layout ----
    float* dinv = (float*)d_ws;                  // N
    int*   ptr  = (int*)d_ws + N;                // N+1
    float* sums = (float*)d_ws + 2 * N + 1;      // 512
    int*   bbase1 = (int*)d_ws + 2 * N + 513;    // nbk+1
    int*   btot   = bbase1 + nbk + 1;            // nbk
    int*   blkoff = btot + nbk;                  // nbk*nb_c
    size_t wt_off = ((size_t)(2 * N + 514 + 2 * nbk) + (size_t)nbk * nb_c + 3) & ~(size_t)3;
    unsigned* wtb = (unsigned*)((int*)d_ws + wt_off);             // 8192
    size_t pk_off = (wt_off + 8192 + 3) & ~(size_t)3;
    unsigned* p1_packed = (unsigned*)((int*)d_ws + pk_off);       // E
    size_t tt_off = (pk_off + (size_t)E + 3) & ~(size_t)3;
    unsigned* p1_tmp = (unsigned*)((int*)d_ws + tt_off);          // tmp(E)/tab(64N)
    unsigned* p1_tab = (unsigned*)((int*)d_ws + tt_off);
    size_t ab_off = (tt_off + tt_words + 3) & ~(size_t)3;
    unsigned* aggb = (unsigned*)((int*)d_ws + ab_off);            // 64N
    size_t need_p1 = (ab_off + (size_t)64 * N) * 4;

    // ---- path-2 layout (4B tmp format) ----
    float* dinv2 = (float*)d_ws;
    int*   ptr2  = (int*)d_ws + N;
    int*   cnt3  = (int*)d_ws + 2 * N + 1;
    float* sums2 = (float*)d_ws + 3 * N + 1;
    int*   bsum2 = (int*)d_ws + 3 * N + 513;
    int*   bbase2 = (int*)d_ws + 3 * N + 1025;
    int*   bcur2  = bbase2 + nbk + 1;
    size_t pk2 = ((size_t)(3 * N + 1026 + 2 * nbk) + 3) & ~(size_t)3;
    unsigned* packed2 = (unsigned*)((int*)d_ws + pk2);            // E
    size_t tt2 = (pk2 + (size_t)E + 3) & ~(size_t)3;
    unsigned* tmp2 = (unsigned*)((int*)d_ws + tt2);
    unsigned* tab2 = (unsigned*)((int*)d_ws + tt2);
    size_t need_full2 = (tt2 + tt_words) * 4;

    // ---- path-3 layout (int2 packed, f32 gather) ----
    int2*  packed3 = (int2*)((int*)d_ws + pk2);                   // 2E
    size_t need_csr3 = (pk2 + (size_t)2 * E) * 4;

    if (nbk <= MAX_BKT && ws_size >= need_p1) {
        k_convW<<<32, 256, 0, stream>>>(W, wtb);
        k_bhist2<<<nb_c, 256, 0, stream>>>(col, blkoff, E, nbk, nb_c);
        k_bscan2a<<<(nbk + 255) / 256, 256, 0, stream>>>(blkoff, btot, nbk, nb_c);
        k_bscan2b<<<1, 1024, 0, stream>>>(btot, bbase1, ptr, sums, nbk, N, E);
        k_passA3<<<nb_c, 256, 0, stream>>>(row, col, ew, blkoff, bbase1, p1_tmp, E, nbk, nb_c);
        k_passB2<<<nbk, 256, 0, stream>>>(p1_tmp, bbase1, p1_packed, ptr, dinv, N);
        k_conv2<<<nconv, 256, 0, stream>>>(nf, dinv, (uint4*)p1_tab, N);
        k_gatherw5<<<nb_w, 256, 0, stream>>>(p1_packed, ptr, dinv, p1_tab, aggb, N);
        k_gemm3b<<<(N + 127) / 128, 256, 0, stream>>>(aggb, wtb, bias, sums, N);
        k_bnfin<<<1, 128, 0, stream>>>(sums, gamma, beta, N);
        k_bnapplyB<<<(int)((n16 + 255) / 256), 256, 0, stream>>>(aggb, sums, out, n16);
        return;
    }

    if (nbk <= MAX_BKT && ws_size >= need_full2) {
        k_init0<<<(max(nbk, 512) + 255) / 256, 256, 0, stream>>>(bcur2, sums2, nbk);
        k_bhist<<<nb_c, 256, 0, stream>>>(col, bcur2, E, nbk);
        k_bscan<<<1, 1024, 0, stream>>>(bcur2, bbase2, bcur2, ptr2, nbk, N, E);
        k_passA2<<<nb_c, 256, 0, stream>>>(row, col, ew, bcur2, tmp2, E, nbk);
        k_passB2<<<nbk, 256, 0, stream>>>(tmp2, bbase2, packed2, ptr2, dinv2, N);
        k_conv2<<<nconv, 256, 0, stream>>>(nf, dinv2, (uint4*)tab2, N);
        k_gatherwF<<<nb_w, 256, 0, stream>>>(packed2, ptr2, dinv2, tab2, out, N);
        k_gemm2<<<(N + 127) / 128, 256, 0, stream>>>(out, W, bias, sums2, N);
        k_bnfin<<<1, 128, 0, stream>>>(sums2, gamma, beta, N);
        k_bnapply<<<nb_v4, 256, 0, stream>>>(out, sums2, (size_t)N * 32);
        return;
    }

    if (ws_size >= need_csr3) {
        k_init<<<nb_n, 256, 0, stream>>>(cnt3, sums2, N);
        k_count<<<nb_e, 256, 0, stream>>>(col, cnt3, E);
        kS1<<<nb_n, 256, 0, stream>>>(cnt3, ptr2, bsum2, N);
        kS2<<<1, 512, 0, stream>>>(bsum2, ptr2, nb_n, N);
        kS3<<<nb_n, 256, 0, stream>>>(ptr2, cnt3, bsum2, N);
        k_fill<<<nb_e, 256, 0, stream>>>(row, col, ew, cnt3, packed3, E);
        k_degw<<<nb_w, 256, 0, stream>>>(packed3, ptr2, dinv2, N);
        k_gather<<<nb_w, 256, 0, stream>>>(packed3, ptr2, dinv2, nf, out, N);
        k_gemm2<<<(N + 127) / 128, 256, 0, stream>>>(out, W, bias, sums2, N);
        k_bnfin<<<1, 128, 0, stream>>>(sums2, gamma, beta, N);
        k_bnapply<<<nb_v4, 256, 0, stream>>>(out, sums2, (size_t)N * 32);
        return;
    }

    {
        float* deg = (float*)d_ws;
        float* sm  = (float*)d_ws + N;
        k_initA<<<nb_n, 256, 0, stream>>>(deg, sm, N);
        k_deg<<<nb_e, 256, 0, stream>>>(col, ew, deg, E);
        k_dinv<<<nb_n, 256, 0, stream>>>(deg, N);
        k_self<<<nb_v4, 256, 0, stream>>>(nf, deg, out, N);
        k_scatter<<<(E + 3) / 4, 256, 0, stream>>>(row, col, ew, deg, nf, out, E);
        k_gemm2<<<(N + 127) / 128, 256, 0, stream>>>(out, W, bias, sm, N);
        k_bnfin<<<1, 128, 0, stream>>>(sm, gamma, beta, N);
        k_bnapply<<<nb_v4, 256, 0, stream>>>(out, sm, (size_t)N * 32);
    }
}